// Round 7
// baseline (2924.402 us; speedup 1.0000x reference)
//
#include <hip/hip_runtime.h>
#include <cstdint>

// ---------------- problem constants ----------------
// S=128 samples (64 x1 + 64 x2) live in the lane dimension of every tensor:
// activations/cotangents/masks are [y][x][ch][s=128] ("CHWN"-style, s innermost).
constexpr int OFF_W1 = 0;        // 64*3*9
constexpr int OFF_B1 = 1728;
constexpr int OFF_W2 = 1792;     // 64*64*9
constexpr int OFF_B2 = 38656;
constexpr int OFF_W3 = 38720;
constexpr int OFF_B3 = 75584;
constexpr int OFF_W4 = 75648;
constexpr int OFF_B4 = 112512;
constexpr int OFF_H  = 112576;   // 1600
constexpr int PJ     = 114176;   // = 223*512

// ---------------- input transpose: [128][3*84*84] -> [3*84*84][128] ----------------
__global__ __launch_bounds__(256) void k_transpose(
    const float* __restrict__ x1, const float* __restrict__ x2, float* __restrict__ xT)
{
    __shared__ float tile[32][33];
    const int c0 = blockIdx.x * 32, s0 = blockIdx.y * 32;
    const int tx = threadIdx.x, ty = threadIdx.y;
#pragma unroll
    for (int k = 0; k < 4; ++k) {
        const int row = s0 + ty + k * 8;          // sample
        const int col = c0 + tx;                  // flat (i,y,x)
        const float* src = (row < 64) ? (x1 + (size_t)row * 21168)
                                      : (x2 + (size_t)(row - 64) * 21168);
        tile[ty + k * 8][tx] = (col < 21168) ? src[col] : 0.f;
    }
    __syncthreads();
#pragma unroll
    for (int k = 0; k < 4; ++k) {
        const int c = c0 + ty + k * 8;
        if (c < 21168) xT[(size_t)c * 128 + (s0 + tx)] = tile[tx][ty + k * 8];
    }
}

// ---------------- weight prep ----------------
// wS_l[i][t][o] = w_l[o][i][t]      (forward, scalar-load friendly)
// wB_l[o][t][i] = w_l[o][i][8-t]    (backward conv-transpose)
__global__ __launch_bounds__(256) void k_wprep(
    const float* __restrict__ w1, const float* __restrict__ w2,
    const float* __restrict__ w3, const float* __restrict__ w4,
    float* __restrict__ wS1, float* __restrict__ wS2, float* __restrict__ wS3,
    float* __restrict__ wS4, float* __restrict__ wB2, float* __restrict__ wB3,
    float* __restrict__ wB4)
{
    const int idx = blockIdx.x * 256 + threadIdx.x;
    if (idx >= 36864) return;
    const int o = idx / 576, rem = idx % 576, i = rem / 9, t = rem % 9;
    wS2[(i * 9 + t) * 64 + o] = w2[idx];
    wS3[(i * 9 + t) * 64 + o] = w3[idx];
    wS4[(i * 9 + t) * 64 + o] = w4[idx];
    wB2[(o * 9 + (8 - t)) * 64 + i] = w2[idx];
    wB3[(o * 9 + (8 - t)) * 64 + i] = w3[idx];
    wB4[(o * 9 + (8 - t)) * 64 + i] = w4[idx];
    if (idx < 1728) {
        const int o1 = idx / 27, r1 = idx % 27, i1 = r1 / 9, t1 = r1 % 9;
        wS1[(i1 * 9 + t1) * 64 + o1] = w1[idx];
    }
}

// ---------------- forward conv3x3(SAME)+bias+relu+maxpool2x2, fused ----------------
// block (128 s-lanes, 2): ty = pooled row within pair. Each thread: OB o's x 2 conv rows x 4 conv cols.
// in strides (floats): i*SI + y*SY + x*SX + lane
template<int CIN, int TIN, int OB, int SI, int SY, int SX>
__global__ __launch_bounds__(256) void k_fwd(
    const float* __restrict__ in, const float* __restrict__ wS,
    const float* __restrict__ bias, float* __restrict__ pout,
    unsigned char* __restrict__ mout)
{
    constexpr int PW = TIN / 2;
    const int lane = threadIdx.x;
    const int x0 = blockIdx.x * 4;
    const int o0 = blockIdx.y * OB;
    const int pr = blockIdx.z * 2 + threadIdx.y;
    if (pr >= PW) return;
    const int cr0 = 2 * pr;

    float acc[OB][2][4];
#pragma unroll
    for (int j = 0; j < OB; ++j)
#pragma unroll
        for (int r = 0; r < 2; ++r)
#pragma unroll
            for (int p = 0; p < 4; ++p) acc[j][r][p] = 0.f;

#pragma unroll 1
    for (int i = 0; i < CIN; ++i) {
        float a[4][6];
#pragma unroll
        for (int rr = 0; rr < 4; ++rr) {
            const int y = cr0 - 1 + rr;
            const bool rok = (unsigned)y < (unsigned)TIN;
#pragma unroll
            for (int cc = 0; cc < 6; ++cc) {
                const int x = x0 - 1 + cc;
                a[rr][cc] = (rok && (unsigned)x < (unsigned)TIN)
                    ? in[(size_t)i * SI + (size_t)y * SY + (size_t)x * SX + lane] : 0.f;
            }
        }
        const float* wrow = wS + (i * 9) * 64 + o0;   // uniform -> s_load
#pragma unroll
        for (int t = 0; t < 9; ++t) {
            const int dy = t / 3, dx = t % 3;
#pragma unroll
            for (int j = 0; j < OB; ++j) {
                const float wv = wrow[t * 64 + j];
#pragma unroll
                for (int r = 0; r < 2; ++r)
#pragma unroll
                    for (int p = 0; p < 4; ++p)
                        acc[j][r][p] = fmaf(wv, a[r + dy][p + dx], acc[j][r][p]);
            }
        }
    }
#pragma unroll
    for (int j = 0; j < OB; ++j) {
        const float b = bias[o0 + j];
#pragma unroll
        for (int q = 0; q < 2; ++q) {
            const int wx = x0 / 2 + q;
            if (wx >= PW) continue;
            const float c00 = fmaxf(acc[j][0][2 * q]     + b, 0.f);
            const float c01 = fmaxf(acc[j][0][2 * q + 1] + b, 0.f);
            const float c10 = fmaxf(acc[j][1][2 * q]     + b, 0.f);
            const float c11 = fmaxf(acc[j][1][2 * q + 1] + b, 0.f);
            float best = c00; int idx = 0;                     // first-strict-max (matches XLA)
            if (c01 > best) { best = c01; idx = 1; }
            if (c10 > best) { best = c10; idx = 2; }
            if (c11 > best) { best = c11; idx = 3; }
            const size_t oi = ((size_t)(pr * PW + wx) * 64 + (o0 + j)) * 128 + lane;
            pout[oi] = best;
            mout[oi] = (unsigned char)(idx | (best > 0.f ? 4 : 0));
        }
    }
}

// ---------------- seed: gamma4 = fc_w[c] reshaped [64][5][5]; J h-segment ----------------
__global__ __launch_bounds__(128) void k_seed(
    const float* __restrict__ fcw, const int* __restrict__ cptr,
    const float* __restrict__ p4, const float* __restrict__ scal_,
    float* __restrict__ g4, float* __restrict__ JT)
{
    const int s = threadIdx.x;
    const int cell = blockIdx.x / 64, o = blockIdx.x % 64;
    const int c = *cptr;
    const int j = o * 25 + cell;                   // CHW flatten of [64][5][5]
    const size_t base = ((size_t)cell * 64 + o) * 128 + s;
    g4[base] = fcw[(size_t)c * 1600 + j];
    JT[(size_t)(OFF_H + j) * 128 + s] = scal_[8] * p4[base];
}

// ---------------- backward: gamma_{l-1} = convT(w_l, u_l), u routed inline ----------------
// gl/ml on TL^2 pooled grid; output dense on TP^2 grid. u_l[y][x][o] = (m==code)?g:0.
template<int TL, int TP, int OB>
__global__ __launch_bounds__(256) void k_bwd(
    const float* __restrict__ gl, const unsigned char* __restrict__ ml,
    const float* __restrict__ wB, float* __restrict__ gout)
{
    const int lane = threadIdx.x;
    const int x0 = blockIdx.x * 4;
    const int i0 = blockIdx.y * OB;
    const int row = blockIdx.z * 2 + threadIdx.y;
    if (row >= TP) return;

    float acc[OB][4];
#pragma unroll
    for (int j = 0; j < OB; ++j)
#pragma unroll
        for (int p = 0; p < 4; ++p) acc[j][p] = 0.f;

#pragma unroll 1
    for (int o = 0; o < 64; ++o) {
        float a[3][6];
#pragma unroll
        for (int rr = 0; rr < 3; ++rr) {
            const int y = row - 1 + rr;
            const bool rok = (unsigned)y < (unsigned)TP;
            const int wy = y >> 1;
            const int yb = (y & 1) << 1;
#pragma unroll
            for (int cc = 0; cc < 6; ++cc) {
                const int x = x0 - 1 + cc;
                float v = 0.f;
                if (rok && (unsigned)x < (unsigned)TP) {
                    const int wx = x >> 1;
                    if (wy < TL && wx < TL) {
                        const size_t base = ((size_t)(wy * TL + wx) * 64 + o) * 128 + lane;
                        const int code = 4 | yb | (x & 1);
                        const int mv = ml[base];
                        const float gv = gl[base];
                        v = (mv == code) ? gv : 0.f;
                    }
                }
                a[rr][cc] = v;
            }
        }
        const float* wrow = wB + (o * 9) * 64 + i0;   // uniform -> s_load
#pragma unroll
        for (int t = 0; t < 9; ++t) {
            const int dy = t / 3, dx = t % 3;
#pragma unroll
            for (int j = 0; j < OB; ++j) {
                const float wv = wrow[t * 64 + j];
#pragma unroll
                for (int p = 0; p < 4; ++p)
                    acc[j][p] = fmaf(wv, a[dy][p + dx], acc[j][p]);
            }
        }
    }
#pragma unroll
    for (int j = 0; j < OB; ++j)
#pragma unroll
        for (int p = 0; p < 4; ++p) {
            const int x = x0 + p;
            if (x < TP)
                gout[((size_t)(row * TP + x) * 64 + (i0 + j)) * 128 + lane] = acc[j][p];
        }
}

// ---------------- weight grads (layers 2..4), pooled-cell form ----------------
// dW[o,i,dy,dx] = sum_{pooled cells} u * h; one (m,g) load pair per pooled cell
// serves its 2x2 dense block. Per thread: 2 o's x 4 i's, 4-row x 4-col register
// window shifted by 2 cols per pooled col. lane = s. Atomic z-split over pooled rows.
template<int TL, int TIN>
__global__ __launch_bounds__(128) void k_wgrad(
    const float* __restrict__ gl, const unsigned char* __restrict__ ml,
    const float* __restrict__ h, const float* __restrict__ scal_,
    const int scalIdx, const int joff, float* __restrict__ JT, const int wychunk)
{
    const int s = threadIdx.x;
    const int o0 = blockIdx.x * 2;     // 32 o-blocks
    const int i0 = blockIdx.y * 4;     // 16 i-blocks
    const int wy0 = blockIdx.z * wychunk;
    const int wy1 = (wy0 + wychunk < TL) ? wy0 + wychunk : TL;

    float acc[2][4][9];
#pragma unroll
    for (int jo = 0; jo < 2; ++jo)
#pragma unroll
        for (int ji = 0; ji < 4; ++ji)
#pragma unroll
            for (int t = 0; t < 9; ++t) acc[jo][ji][t] = 0.f;

#pragma unroll 1
    for (int wy = wy0; wy < wy1; ++wy) {
        // window rows ry = 2wy-1 .. 2wy+2 ; slots hold cols 2wx-1 .. 2wx+2
        float hw[4][4][4];
#pragma unroll
        for (int ji = 0; ji < 4; ++ji)
#pragma unroll
            for (int r = 0; r < 4; ++r) {
                const int ry = 2 * wy - 1 + r;
                const bool rok = (unsigned)ry < (unsigned)TIN;
                hw[ji][r][0] = 0.f;   // col -1
#pragma unroll
                for (int c = 1; c < 4; ++c) {
                    const int col = c - 1;  // cols 0,1,2 (< TIN always)
                    hw[ji][r][c] = rok
                        ? h[((size_t)(ry * TIN + col) * 64 + i0 + ji) * 128 + s] : 0.f;
                }
            }
#pragma unroll 1
        for (int wx = 0; wx < TL; ++wx) {
            // one (m,g) pair per pooled cell per jo -> 4 routed dense values
            float uu[2][2][2];
#pragma unroll
            for (int jo = 0; jo < 2; ++jo) {
                const size_t base = ((size_t)(wy * TL + wx) * 64 + o0 + jo) * 128 + s;
                const int mv = ml[base];
                const float gv = gl[base];
#pragma unroll
                for (int yy = 0; yy < 2; ++yy)
#pragma unroll
                    for (int xx = 0; xx < 2; ++xx)
                        uu[jo][yy][xx] = (mv == (4 | (yy << 1) | xx)) ? gv : 0.f;
            }
            // dense (y,x) = (2wy+yy, 2wx+xx); h[y+dy-1][x+dx-1] = hw[r=yy+dy][slot=xx+dx]
#pragma unroll
            for (int jo = 0; jo < 2; ++jo)
#pragma unroll
                for (int yy = 0; yy < 2; ++yy)
#pragma unroll
                    for (int xx = 0; xx < 2; ++xx) {
                        const float uv = uu[jo][yy][xx];
#pragma unroll
                        for (int ji = 0; ji < 4; ++ji)
#pragma unroll
                            for (int dy = 0; dy < 3; ++dy)
#pragma unroll
                                for (int dx = 0; dx < 3; ++dx)
                                    acc[jo][ji][dy * 3 + dx] =
                                        fmaf(uv, hw[ji][yy + dy][xx + dx],
                                             acc[jo][ji][dy * 3 + dx]);
                    }
            // shift window 2 cols; load cols 2wx+3, 2wx+4
            if (wx + 1 < TL) {
#pragma unroll
                for (int ji = 0; ji < 4; ++ji)
#pragma unroll
                    for (int r = 0; r < 4; ++r) {
                        hw[ji][r][0] = hw[ji][r][2];
                        hw[ji][r][1] = hw[ji][r][3];
                    }
#pragma unroll
                for (int c = 2; c < 4; ++c) {
                    const int col = 2 * wx + 1 + c;   // 2wx+3, 2wx+4
                    const bool cok = col < TIN;
#pragma unroll
                    for (int ji = 0; ji < 4; ++ji)
#pragma unroll
                        for (int r = 0; r < 4; ++r) {
                            const int ry = 2 * wy - 1 + r;
                            hw[ji][r][c] = (cok && (unsigned)ry < (unsigned)TIN)
                                ? h[((size_t)(ry * TIN + col) * 64 + i0 + ji) * 128 + s]
                                : 0.f;
                        }
                }
            }
        }
    }
    const float sc = scal_[scalIdx];
#pragma unroll
    for (int jo = 0; jo < 2; ++jo)
#pragma unroll
        for (int ji = 0; ji < 4; ++ji)
#pragma unroll
            for (int t = 0; t < 9; ++t) {
                const int feat = joff + ((o0 + jo) * 64 + (i0 + ji)) * 9 + t;
                atomicAdd(&JT[(size_t)feat * 128 + s], sc * acc[jo][ji][t]);
            }
}

// ---------------- weight grad layer 1: dense-routed u, lane=s, coalesced ----------------
// grid: (32 o-pairs, 42 pooled rows wy), block 128. Covers dense rows y=2wy, 2wy+1.
// Atomic split over wy into pre-zeroed W1 segment of JT. xT: [3][84][84][128].
__global__ __launch_bounds__(128) void k_wgrad1(
    const float* __restrict__ g1, const unsigned char* __restrict__ m1,
    const float* __restrict__ xT, const float* __restrict__ scal_,
    float* __restrict__ JT)
{
    const int s = threadIdx.x;
    const int o0 = blockIdx.x * 2;
    const int wy = blockIdx.y;

    float acc[2][3][9];
#pragma unroll
    for (int oo = 0; oo < 2; ++oo)
#pragma unroll
        for (int i = 0; i < 3; ++i)
#pragma unroll
            for (int t = 0; t < 9; ++t) acc[oo][i][t] = 0.f;

    // window rows ry = 2wy-1 .. 2wy+2 ; rotating col window idx (k+dx+2)%3
    float hw[3][4][3];
#pragma unroll
    for (int i = 0; i < 3; ++i)
#pragma unroll
        for (int r = 0; r < 4; ++r) {
            const int ry = 2 * wy - 1 + r;
            hw[i][r][2] = 0.f;   // col -1
            hw[i][r][1] = 0.f;
            hw[i][r][0] = ((unsigned)ry < 84u)
                ? xT[((size_t)i * 7056 + ry * 84) * 128 + s] : 0.f;  // col 0
        }
    const int cellrow = wy * 42;

#pragma unroll 1
    for (int xb = 0; xb < 84; xb += 3) {
#pragma unroll
        for (int k = 0; k < 3; ++k) {
            const int x = xb + k;
            const int xn = x + 1;
            const bool cok = xn < 84;
#pragma unroll
            for (int i = 0; i < 3; ++i)
#pragma unroll
                for (int r = 0; r < 4; ++r) {
                    const int ry = 2 * wy - 1 + r;
                    hw[i][r][(k + 1) % 3] = (cok && (unsigned)ry < 84u)
                        ? xT[((size_t)i * 7056 + ry * 84 + xn) * 128 + s] : 0.f;
                }
            const int wx = x >> 1;
            const int xbit = x & 1;
            float u[2][2];
#pragma unroll
            for (int oo = 0; oo < 2; ++oo) {
                const size_t base = ((size_t)(cellrow + wx) * 64 + o0 + oo) * 128 + s;
                const int mv = m1[base];
                const float gv = g1[base];
                u[oo][0] = (mv == (4 | 0 | xbit)) ? gv : 0.f;   // dense row even
                u[oo][1] = (mv == (4 | 2 | xbit)) ? gv : 0.f;   // dense row odd
            }
#pragma unroll
            for (int oo = 0; oo < 2; ++oo)
#pragma unroll
                for (int yy = 0; yy < 2; ++yy)
#pragma unroll
                    for (int i = 0; i < 3; ++i)
#pragma unroll
                        for (int dy = 0; dy < 3; ++dy)
#pragma unroll
                            for (int dx = 0; dx < 3; ++dx)
                                acc[oo][i][dy * 3 + dx] =
                                    fmaf(u[oo][yy], hw[i][yy + dy][(k + dx + 2) % 3],
                                         acc[oo][i][dy * 3 + dx]);
        }
    }
    const float sc = scal_[0];
#pragma unroll
    for (int oo = 0; oo < 2; ++oo)
#pragma unroll
        for (int i = 0; i < 3; ++i)
#pragma unroll
            for (int t = 0; t < 9; ++t)
                atomicAdd(&JT[(size_t)(OFF_W1 + (o0 + oo) * 27 + i * 9 + t) * 128 + s],
                          sc * acc[oo][i][t]);
}

// ---------------- bias grads: partials then reduce ----------------
__global__ __launch_bounds__(128) void k_dbpart(
    const float* __restrict__ g1, const float* __restrict__ g2,
    const float* __restrict__ g3, const float* __restrict__ g4,
    const unsigned char* __restrict__ m1, const unsigned char* __restrict__ m2,
    const unsigned char* __restrict__ m3, const unsigned char* __restrict__ m4,
    float* __restrict__ part)
{
    const int s = threadIdx.x;
    const int o = blockIdx.x, chunk = blockIdx.y, layer = blockIdx.z;
    const float* g; const unsigned char* m; int nc;
    if (layer == 0)      { g = g1; m = m1; nc = 1764; }
    else if (layer == 1) { g = g2; m = m2; nc = 441; }
    else if (layer == 2) { g = g3; m = m3; nc = 100; }
    else                 { g = g4; m = m4; nc = 25; }
    const int c0 = chunk * nc / 4, c1 = (chunk + 1) * nc / 4;
    float acc = 0.f;
    for (int cell = c0; cell < c1; ++cell) {
        const size_t base = ((size_t)cell * 64 + o) * 128 + s;
        acc += (m[base] & 4) ? g[base] : 0.f;
    }
    part[((size_t)(layer * 4 + chunk) * 64 + o) * 128 + s] = acc;
}

__global__ __launch_bounds__(256) void k_dbred(
    const float* __restrict__ part, const float* __restrict__ scal_,
    float* __restrict__ JT)
{
    const int idx = blockIdx.x * 256 + threadIdx.x;   // 4*64*128
    const int layer = idx >> 13, o = (idx >> 7) & 63, s = idx & 127;
    float v = 0.f;
#pragma unroll
    for (int ch = 0; ch < 4; ++ch)
        v += part[((size_t)(layer * 4 + ch) * 64 + o) * 128 + s];
    const int offb[4] = {OFF_B1, OFF_B2, OFF_B3, OFF_B4};
    JT[(size_t)(offb[layer] + o) * 128 + s] = scal_[2 * layer + 1] * v;
}

// ---------------- NTK GEMM: per-block partials, then reduce (+fc_b const) ----------------
constexpr int NTK_BLOCKS = 446;   // 446 * 8 * 32 = 114176 = PJ
__global__ __launch_bounds__(256) void k_ntk(const float* __restrict__ JT,
                                             float* __restrict__ part)
{
    __shared__ float As[32][64], Bs[32][64];
    const int tx = threadIdx.x, ty = threadIdx.y;
    const int t = ty * 16 + tx;
    float acc[4][4];
#pragma unroll
    for (int a = 0; a < 4; ++a)
#pragma unroll
        for (int b = 0; b < 4; ++b) acc[a][b] = 0.f;

    for (int ch = 0; ch < 8; ++ch) {
        const int k0 = (blockIdx.x * 8 + ch) * 32;
        __syncthreads();
#pragma unroll
        for (int q = 0; q < 4; ++q) {
            const int fidx = q * 256 + t;          // float4 index within [32][128]
            const int row = fidx >> 5;
            const int c4 = (fidx & 31) * 4;
            const float4 v = *(const float4*)&JT[(size_t)(k0 + row) * 128 + c4];
            if (c4 < 64) *(float4*)&As[row][c4] = v;
            else         *(float4*)&Bs[row][c4 - 64] = v;
        }
        __syncthreads();
#pragma unroll
        for (int k = 0; k < 32; ++k) {
            const float4 av = *(const float4*)&As[k][ty * 4];
            const float4 bv = *(const float4*)&Bs[k][tx * 4];
            acc[0][0] = fmaf(av.x, bv.x, acc[0][0]);
            acc[0][1] = fmaf(av.x, bv.y, acc[0][1]);
            acc[0][2] = fmaf(av.x, bv.z, acc[0][2]);
            acc[0][3] = fmaf(av.x, bv.w, acc[0][3]);
            acc[1][0] = fmaf(av.y, bv.x, acc[1][0]);
            acc[1][1] = fmaf(av.y, bv.y, acc[1][1]);
            acc[1][2] = fmaf(av.y, bv.z, acc[1][2]);
            acc[1][3] = fmaf(av.y, bv.w, acc[1][3]);
            acc[2][0] = fmaf(av.z, bv.x, acc[2][0]);
            acc[2][1] = fmaf(av.z, bv.y, acc[2][1]);
            acc[2][2] = fmaf(av.z, bv.z, acc[2][2]);
            acc[2][3] = fmaf(av.z, bv.w, acc[2][3]);
            acc[3][0] = fmaf(av.w, bv.x, acc[3][0]);
            acc[3][1] = fmaf(av.w, bv.y, acc[3][1]);
            acc[3][2] = fmaf(av.w, bv.z, acc[3][2]);
            acc[3][3] = fmaf(av.w, bv.w, acc[3][3]);
        }
    }
#pragma unroll
    for (int a = 0; a < 4; ++a)
#pragma unroll
        for (int b = 0; b < 4; ++b)
            part[(size_t)blockIdx.x * 4096 + (ty * 4 + a) * 64 + (tx * 4 + b)] = acc[a][b];
}

__global__ __launch_bounds__(256) void k_ntkred(
    const float* __restrict__ part, const float* __restrict__ scal_,
    float* __restrict__ out)
{
    const int t = blockIdx.x * 256 + threadIdx.x;   // 4096
    float v = scal_[9] * scal_[9];
    for (int ck = 0; ck < NTK_BLOCKS; ++ck) v += part[(size_t)ck * 4096 + t];
    out[t] = v;
}

// ---------------- host launch ----------------
extern "C" void kernel_launch(void* const* d_in, const int* in_sizes, int n_in,
                              void* d_out, int out_size, void* d_ws, size_t ws_size,
                              hipStream_t stream)
{
    const void* IN[14];
    if (n_in >= 14 && in_sizes[2] == 10 && in_sizes[3] == 1) {
        for (int k = 0; k < 14; ++k) IN[k] = d_in[k];
    } else {
        IN[0] = d_in[0]; IN[1] = d_in[1];
        IN[2] = d_in[12]; IN[3] = d_in[13];
        for (int k = 0; k < 8; ++k) IN[4 + k] = d_in[2 + k];
        IN[12] = d_in[10]; IN[13] = d_in[11];
    }
    const float* x1   = (const float*)IN[0];
    const float* x2   = (const float*)IN[1];
    const float* scal = (const float*)IN[2];
    const int*   cp   = (const int*)IN[3];
    const float* w1 = (const float*)IN[4];  const float* b1 = (const float*)IN[5];
    const float* w2 = (const float*)IN[6];  const float* b2 = (const float*)IN[7];
    const float* w3 = (const float*)IN[8];  const float* b3 = (const float*)IN[9];
    const float* w4 = (const float*)IN[10]; const float* b4 = (const float*)IN[11];
    const float* fcw = (const float*)IN[12];
    float* out = (float*)d_out;

    char* base = (char*)d_ws;
    size_t off = 0;
    auto alloc = [&](size_t bytes) -> char* {
        char* p = base + off;
        off = (off + bytes + 255) & ~(size_t)255;
        return p;
    };
    // JT first. xT (10.84 MB) aliases JT's W3 segment (features 38720..59888,
    // inside W3 [38720,75584)): xT consumers are k_fwd<3,84> and k_wgrad1; after
    // k_wgrad1, W3 is memset to 0 and k_wgrad<10,21> atomically accumulates it.
    // W1/B1/W2 (head memset) and W4 (second head memset) do not overlap xT.
    float* JT = (float*)alloc((size_t)PJ * 128 * 4);      // 58.5 MB
    float* xT = JT + (size_t)OFF_W3 * 128;
    float* p1 = (float*)alloc((size_t)1764 * 64 * 128 * 4);
    float* p2 = (float*)alloc((size_t)441  * 64 * 128 * 4);
    float* p3 = (float*)alloc((size_t)100  * 64 * 128 * 4);
    float* p4 = (float*)alloc((size_t)25   * 64 * 128 * 4);
    unsigned char* m1 = (unsigned char*)alloc((size_t)1764 * 64 * 128);
    unsigned char* m2 = (unsigned char*)alloc((size_t)441  * 64 * 128);
    unsigned char* m3 = (unsigned char*)alloc((size_t)100  * 64 * 128);
    unsigned char* m4 = (unsigned char*)alloc((size_t)25   * 64 * 128);
    float* g1 = (float*)alloc((size_t)1764 * 64 * 128 * 4);
    float* g2 = (float*)alloc((size_t)441  * 64 * 128 * 4);
    float* g3 = (float*)alloc((size_t)100  * 64 * 128 * 4);
    float* g4 = (float*)alloc((size_t)25   * 64 * 128 * 4);
    float* wS1 = (float*)alloc(1728 * 4);
    float* wS2 = (float*)alloc(36864 * 4);
    float* wS3 = (float*)alloc(36864 * 4);
    float* wS4 = (float*)alloc(36864 * 4);
    float* wB2 = (float*)alloc(36864 * 4);
    float* wB3 = (float*)alloc(36864 * 4);
    float* wB4 = (float*)alloc(36864 * 4);
    float* dbp = (float*)alloc((size_t)16 * 64 * 128 * 4);
    // NTK partials (446*16KB = 7.3 MB) alias g1 (57.8 MB): g1 dead after k_dbpart.
    float* ntkp = g1;
    (void)ws_size;

    // ---- zero atomic-accumulated segments: W1+B1+W2 and W4 ----
    hipMemsetAsync(JT, 0, (size_t)OFF_B2 * 128 * 4, stream);
    hipMemsetAsync(JT + (size_t)OFF_W4 * 128, 0, (size_t)36864 * 128 * 4, stream);

    // ---- prep ----
    k_transpose<<<dim3(662, 4), dim3(32, 8), 0, stream>>>(x1, x2, xT);
    k_wprep<<<144, 256, 0, stream>>>(w1, w2, w3, w4, wS1, wS2, wS3, wS4, wB2, wB3, wB4);

    // ---- forward (xT: [3][84][84][128]; p_l: [y][x][64][128]) ----
    k_fwd<3, 84, 8, 84 * 84 * 128, 84 * 128, 128>
        <<<dim3(21, 8, 21), dim3(128, 2), 0, stream>>>(xT, wS1, b1, p1, m1);
    k_fwd<64, 42, 8, 128, 42 * 64 * 128, 64 * 128>
        <<<dim3(11, 8, 11), dim3(128, 2), 0, stream>>>(p1, wS2, b2, p2, m2);
    k_fwd<64, 21, 4, 128, 21 * 64 * 128, 64 * 128>
        <<<dim3(5, 16, 5), dim3(128, 2), 0, stream>>>(p2, wS3, b3, p3, m3);
    k_fwd<64, 10, 4, 128, 10 * 64 * 128, 64 * 128>
        <<<dim3(3, 16, 3), dim3(128, 2), 0, stream>>>(p3, wS4, b4, p4, m4);

    // ---- seed gamma4 + h segment ----
    k_seed<<<1600, 128, 0, stream>>>(fcw, cp, p4, scal, g4, JT);

    // ---- backward cotangents (dense, routing inline) ----
    k_bwd<5, 10, 8><<<dim3(3, 8, 5),  dim3(128, 2), 0, stream>>>(g4, m4, wB4, g3);
    k_bwd<10, 21, 8><<<dim3(6, 8, 11), dim3(128, 2), 0, stream>>>(g3, m3, wB3, g2);
    k_bwd<21, 42, 8><<<dim3(11, 8, 21), dim3(128, 2), 0, stream>>>(g2, m2, wB2, g1);

    // ---- weight grads (pooled-cell form; atomics into pre-zeroed segments) ----
    k_wgrad<5, 10><<<dim3(32, 16, 2), 128, 0, stream>>>(g4, m4, p3, scal, 6, OFF_W4, JT, 3);
    k_wgrad1<<<dim3(32, 42), 128, 0, stream>>>(g1, m1, xT, scal, JT);
    // xT retired; zero W3 then accumulate it
    hipMemsetAsync(JT + (size_t)OFF_W3 * 128, 0, (size_t)36864 * 128 * 4, stream);
    k_wgrad<10, 21><<<dim3(32, 16, 2), 128, 0, stream>>>(g3, m3, p2, scal, 4, OFF_W3, JT, 5);
    k_wgrad<21, 42><<<dim3(32, 16, 3), 128, 0, stream>>>(g2, m2, p1, scal, 2, OFF_W2, JT, 7);

    // ---- bias grads ----
    k_dbpart<<<dim3(64, 4, 4), 128, 0, stream>>>(g1, g2, g3, g4, m1, m2, m3, m4, dbp);
    k_dbred<<<128, 256, 0, stream>>>(dbp, scal, JT);

    // ---- K = JT1^T . JT2 + s_fcb^2 (ntkp aliases g1; g1 dead after dbpart) ----
    k_ntk<<<NTK_BLOCKS, dim3(16, 16), 0, stream>>>(JT, ntkp);
    k_ntkred<<<16, 256, 0, stream>>>(ntkp, scal, out);
}

// Round 8
// 2433.672 us; speedup vs baseline: 1.2016x; 1.2016x over previous
//
#include <hip/hip_runtime.h>
#include <cstdint>

// ---------------- problem constants ----------------
// S=128 samples (64 x1 + 64 x2) live in the lane dimension of every tensor:
// activations/cotangents/masks are [y][x][ch][s=128] ("CHWN"-style, s innermost).
constexpr int OFF_W1 = 0;        // 64*3*9
constexpr int OFF_B1 = 1728;
constexpr int OFF_W2 = 1792;     // 64*64*9
constexpr int OFF_B2 = 38656;
constexpr int OFF_W3 = 38720;
constexpr int OFF_B3 = 75584;
constexpr int OFF_W4 = 75648;
constexpr int OFF_B4 = 112512;
constexpr int OFF_H  = 112576;   // 1600
constexpr int PJ     = 114176;   // = 223*512

// ---------------- input transpose: [128][3*84*84] -> [3*84*84][128] ----------------
__global__ __launch_bounds__(256) void k_transpose(
    const float* __restrict__ x1, const float* __restrict__ x2, float* __restrict__ xT)
{
    __shared__ float tile[32][33];
    const int c0 = blockIdx.x * 32, s0 = blockIdx.y * 32;
    const int tx = threadIdx.x, ty = threadIdx.y;
#pragma unroll
    for (int k = 0; k < 4; ++k) {
        const int row = s0 + ty + k * 8;          // sample
        const int col = c0 + tx;                  // flat (i,y,x)
        const float* src = (row < 64) ? (x1 + (size_t)row * 21168)
                                      : (x2 + (size_t)(row - 64) * 21168);
        tile[ty + k * 8][tx] = (col < 21168) ? src[col] : 0.f;
    }
    __syncthreads();
#pragma unroll
    for (int k = 0; k < 4; ++k) {
        const int c = c0 + ty + k * 8;
        if (c < 21168) xT[(size_t)c * 128 + (s0 + tx)] = tile[tx][ty + k * 8];
    }
}

// ---------------- weight prep ----------------
// wS_l[i][t][o] = w_l[o][i][t]      (forward, scalar-load friendly)
// wB_l[o][t][i] = w_l[o][i][8-t]    (backward conv-transpose)
__global__ __launch_bounds__(256) void k_wprep(
    const float* __restrict__ w1, const float* __restrict__ w2,
    const float* __restrict__ w3, const float* __restrict__ w4,
    float* __restrict__ wS1, float* __restrict__ wS2, float* __restrict__ wS3,
    float* __restrict__ wS4, float* __restrict__ wB2, float* __restrict__ wB3,
    float* __restrict__ wB4)
{
    const int idx = blockIdx.x * 256 + threadIdx.x;
    if (idx >= 36864) return;
    const int o = idx / 576, rem = idx % 576, i = rem / 9, t = rem % 9;
    wS2[(i * 9 + t) * 64 + o] = w2[idx];
    wS3[(i * 9 + t) * 64 + o] = w3[idx];
    wS4[(i * 9 + t) * 64 + o] = w4[idx];
    wB2[(o * 9 + (8 - t)) * 64 + i] = w2[idx];
    wB3[(o * 9 + (8 - t)) * 64 + i] = w3[idx];
    wB4[(o * 9 + (8 - t)) * 64 + i] = w4[idx];
    if (idx < 1728) {
        const int o1 = idx / 27, r1 = idx % 27, i1 = r1 / 9, t1 = r1 % 9;
        wS1[(i1 * 9 + t1) * 64 + o1] = w1[idx];
    }
}

// ---------------- forward conv3x3(SAME)+bias+relu+maxpool2x2, fused ----------------
// block (128 s-lanes, 2): ty = pooled row within pair. Each thread: OB o's x 2 conv rows x 4 conv cols.
// in strides (floats): i*SI + y*SY + x*SX + lane
template<int CIN, int TIN, int OB, int SI, int SY, int SX>
__global__ __launch_bounds__(256) void k_fwd(
    const float* __restrict__ in, const float* __restrict__ wS,
    const float* __restrict__ bias, float* __restrict__ pout,
    unsigned char* __restrict__ mout)
{
    constexpr int PW = TIN / 2;
    const int lane = threadIdx.x;
    const int x0 = blockIdx.x * 4;
    const int o0 = blockIdx.y * OB;
    const int pr = blockIdx.z * 2 + threadIdx.y;
    if (pr >= PW) return;
    const int cr0 = 2 * pr;

    float acc[OB][2][4];
#pragma unroll
    for (int j = 0; j < OB; ++j)
#pragma unroll
        for (int r = 0; r < 2; ++r)
#pragma unroll
            for (int p = 0; p < 4; ++p) acc[j][r][p] = 0.f;

#pragma unroll 1
    for (int i = 0; i < CIN; ++i) {
        float a[4][6];
#pragma unroll
        for (int rr = 0; rr < 4; ++rr) {
            const int y = cr0 - 1 + rr;
            const bool rok = (unsigned)y < (unsigned)TIN;
#pragma unroll
            for (int cc = 0; cc < 6; ++cc) {
                const int x = x0 - 1 + cc;
                a[rr][cc] = (rok && (unsigned)x < (unsigned)TIN)
                    ? in[(size_t)i * SI + (size_t)y * SY + (size_t)x * SX + lane] : 0.f;
            }
        }
        const float* wrow = wS + (i * 9) * 64 + o0;   // uniform -> s_load
#pragma unroll
        for (int t = 0; t < 9; ++t) {
            const int dy = t / 3, dx = t % 3;
#pragma unroll
            for (int j = 0; j < OB; ++j) {
                const float wv = wrow[t * 64 + j];
#pragma unroll
                for (int r = 0; r < 2; ++r)
#pragma unroll
                    for (int p = 0; p < 4; ++p)
                        acc[j][r][p] = fmaf(wv, a[r + dy][p + dx], acc[j][r][p]);
            }
        }
    }
#pragma unroll
    for (int j = 0; j < OB; ++j) {
        const float b = bias[o0 + j];
#pragma unroll
        for (int q = 0; q < 2; ++q) {
            const int wx = x0 / 2 + q;
            if (wx >= PW) continue;
            const float c00 = fmaxf(acc[j][0][2 * q]     + b, 0.f);
            const float c01 = fmaxf(acc[j][0][2 * q + 1] + b, 0.f);
            const float c10 = fmaxf(acc[j][1][2 * q]     + b, 0.f);
            const float c11 = fmaxf(acc[j][1][2 * q + 1] + b, 0.f);
            float best = c00; int idx = 0;                     // first-strict-max (matches XLA)
            if (c01 > best) { best = c01; idx = 1; }
            if (c10 > best) { best = c10; idx = 2; }
            if (c11 > best) { best = c11; idx = 3; }
            const size_t oi = ((size_t)(pr * PW + wx) * 64 + (o0 + j)) * 128 + lane;
            pout[oi] = best;
            mout[oi] = (unsigned char)(idx | (best > 0.f ? 4 : 0));
        }
    }
}

// ---------------- seed: gamma4 = fc_w[c] reshaped [64][5][5]; J h-segment ----------------
__global__ __launch_bounds__(128) void k_seed(
    const float* __restrict__ fcw, const int* __restrict__ cptr,
    const float* __restrict__ p4, const float* __restrict__ scal_,
    float* __restrict__ g4, float* __restrict__ JT)
{
    const int s = threadIdx.x;
    const int cell = blockIdx.x / 64, o = blockIdx.x % 64;
    const int c = *cptr;
    const int j = o * 25 + cell;                   // CHW flatten of [64][5][5]
    const size_t base = ((size_t)cell * 64 + o) * 128 + s;
    g4[base] = fcw[(size_t)c * 1600 + j];
    JT[(size_t)(OFF_H + j) * 128 + s] = scal_[8] * p4[base];
}

// ---------------- backward: gamma_{l-1} = convT(w_l, u_l), u routed inline ----------------
// gl/ml on TL^2 pooled grid; output dense on TP^2 grid. u_l[y][x][o] = (m==code)?g:0.
template<int TL, int TP, int OB>
__global__ __launch_bounds__(256) void k_bwd(
    const float* __restrict__ gl, const unsigned char* __restrict__ ml,
    const float* __restrict__ wB, float* __restrict__ gout)
{
    const int lane = threadIdx.x;
    const int x0 = blockIdx.x * 4;
    const int i0 = blockIdx.y * OB;
    const int row = blockIdx.z * 2 + threadIdx.y;
    if (row >= TP) return;

    float acc[OB][4];
#pragma unroll
    for (int j = 0; j < OB; ++j)
#pragma unroll
        for (int p = 0; p < 4; ++p) acc[j][p] = 0.f;

#pragma unroll 1
    for (int o = 0; o < 64; ++o) {
        float a[3][6];
#pragma unroll
        for (int rr = 0; rr < 3; ++rr) {
            const int y = row - 1 + rr;
            const bool rok = (unsigned)y < (unsigned)TP;
            const int wy = y >> 1;
            const int yb = (y & 1) << 1;
#pragma unroll
            for (int cc = 0; cc < 6; ++cc) {
                const int x = x0 - 1 + cc;
                float v = 0.f;
                if (rok && (unsigned)x < (unsigned)TP) {
                    const int wx = x >> 1;
                    if (wy < TL && wx < TL) {
                        const size_t base = ((size_t)(wy * TL + wx) * 64 + o) * 128 + lane;
                        const int code = 4 | yb | (x & 1);
                        const int mv = ml[base];
                        const float gv = gl[base];
                        v = (mv == code) ? gv : 0.f;
                    }
                }
                a[rr][cc] = v;
            }
        }
        const float* wrow = wB + (o * 9) * 64 + i0;   // uniform -> s_load
#pragma unroll
        for (int t = 0; t < 9; ++t) {
            const int dy = t / 3, dx = t % 3;
#pragma unroll
            for (int j = 0; j < OB; ++j) {
                const float wv = wrow[t * 64 + j];
#pragma unroll
                for (int p = 0; p < 4; ++p)
                    acc[j][p] = fmaf(wv, a[dy][p + dx], acc[j][p]);
            }
        }
    }
#pragma unroll
    for (int j = 0; j < OB; ++j)
#pragma unroll
        for (int p = 0; p < 4; ++p) {
            const int x = x0 + p;
            if (x < TP)
                gout[((size_t)(row * TP + x) * 64 + (i0 + j)) * 128 + lane] = acc[j][p];
        }
}

// ---------------- weight grads (layers 2..4): dW[o,i,t] = sum_z u[z][o]*h[z+t-1][i] ----------------
// u routed inline from (gl,ml) on TL^2; h on TIN^2. Per thread: 2o x 2i x 9 acc, lane = s.
// Round-6 form (44 VGPR); occupancy raised via dense-row z-split (atomic into
// pre-zeroed segments). 152-VGPR pooled-cell variant regressed (round 7).
template<int TL, int TIN>
__global__ __launch_bounds__(128) void k_wgrad(
    const float* __restrict__ gl, const unsigned char* __restrict__ ml,
    const float* __restrict__ h, const float* __restrict__ scal_,
    const int scalIdx, const int joff, float* __restrict__ JT, const int ychunk)
{
    const int s = threadIdx.x;
    const int o0 = blockIdx.x * 2, i0 = blockIdx.y * 2;
    const int y0 = blockIdx.z * ychunk;
    const int y1 = (y0 + ychunk < TIN) ? y0 + ychunk : TIN;

    float acc[2][2][9];
#pragma unroll
    for (int a = 0; a < 2; ++a)
#pragma unroll
        for (int b = 0; b < 2; ++b)
#pragma unroll
            for (int t = 0; t < 9; ++t) acc[a][b][t] = 0.f;

#pragma unroll 1
    for (int y = y0; y < y1; ++y) {
        const int wy = y >> 1;
        const int ybit = (y & 1) << 1;
        float hw[2][3][3];                       // [i][dy][col%3] rotating window
#pragma unroll
        for (int ji = 0; ji < 2; ++ji)
#pragma unroll
            for (int dy = 0; dy < 3; ++dy) {
                const int ry = y + dy - 1;
                const bool rok = (unsigned)ry < (unsigned)TIN;
                hw[ji][dy][2] = 0.f;             // col -1
                hw[ji][dy][1] = 0.f;
                hw[ji][dy][0] = rok ? h[((size_t)(ry * TIN) * 64 + i0 + ji) * 128 + s] : 0.f;
            }
#pragma unroll 1
        for (int xb = 0; xb < ((TIN + 2) / 3) * 3; xb += 3) {
#pragma unroll
            for (int k = 0; k < 3; ++k) {
                const int x = xb + k;
                const int xn = x + 1;
                const bool cok = xn < TIN;
#pragma unroll
                for (int ji = 0; ji < 2; ++ji)
#pragma unroll
                    for (int dy = 0; dy < 3; ++dy) {
                        const int ry = y + dy - 1;
                        hw[ji][dy][(k + 1) % 3] =
                            (cok && (unsigned)ry < (unsigned)TIN)
                                ? h[((size_t)(ry * TIN + xn) * 64 + i0 + ji) * 128 + s] : 0.f;
                    }
                if (x < TIN) {
                    const int wx = x >> 1;
                    const bool uok = (wy < TL) && (wx < TL);
                    const int code = 4 | ybit | (x & 1);
                    float u[2] = {0.f, 0.f};
                    if (uok) {
#pragma unroll
                        for (int jo = 0; jo < 2; ++jo) {
                            const size_t base = ((size_t)(wy * TL + wx) * 64 + o0 + jo) * 128 + s;
                            const int mv = ml[base];
                            const float gv = gl[base];
                            u[jo] = (mv == code) ? gv : 0.f;
                        }
                    }
#pragma unroll
                    for (int jo = 0; jo < 2; ++jo)
#pragma unroll
                        for (int ji = 0; ji < 2; ++ji)
#pragma unroll
                            for (int dy = 0; dy < 3; ++dy)
#pragma unroll
                                for (int dx = 0; dx < 3; ++dx)
                                    acc[jo][ji][dy * 3 + dx] =
                                        fmaf(u[jo], hw[ji][dy][(k + dx + 2) % 3],
                                             acc[jo][ji][dy * 3 + dx]);
                }
            }
        }
    }
    const float sc = scal_[scalIdx];
#pragma unroll
    for (int jo = 0; jo < 2; ++jo)
#pragma unroll
        for (int ji = 0; ji < 2; ++ji)
#pragma unroll
            for (int t = 0; t < 9; ++t) {
                const int feat = joff + ((o0 + jo) * 64 + (i0 + ji)) * 9 + t;
                atomicAdd(&JT[(size_t)feat * 128 + s], sc * acc[jo][ji][t]);
            }
}

// ---------------- weight grad layer 1: dense-routed u, lane=s, coalesced ----------------
// grid: (32 o-pairs, 42 pooled rows wy), block 128. Covers dense rows y=2wy, 2wy+1.
// Atomic split over wy into pre-zeroed W1 segment of JT. xT: [3][84][84][128].
__global__ __launch_bounds__(128) void k_wgrad1(
    const float* __restrict__ g1, const unsigned char* __restrict__ m1,
    const float* __restrict__ xT, const float* __restrict__ scal_,
    float* __restrict__ JT)
{
    const int s = threadIdx.x;
    const int o0 = blockIdx.x * 2;
    const int wy = blockIdx.y;

    float acc[2][3][9];
#pragma unroll
    for (int oo = 0; oo < 2; ++oo)
#pragma unroll
        for (int i = 0; i < 3; ++i)
#pragma unroll
            for (int t = 0; t < 9; ++t) acc[oo][i][t] = 0.f;

    // window rows ry = 2wy-1 .. 2wy+2 ; rotating col window idx (k+dx+2)%3
    float hw[3][4][3];
#pragma unroll
    for (int i = 0; i < 3; ++i)
#pragma unroll
        for (int r = 0; r < 4; ++r) {
            const int ry = 2 * wy - 1 + r;
            hw[i][r][2] = 0.f;   // col -1
            hw[i][r][1] = 0.f;
            hw[i][r][0] = ((unsigned)ry < 84u)
                ? xT[((size_t)i * 7056 + ry * 84) * 128 + s] : 0.f;  // col 0
        }
    const int cellrow = wy * 42;

#pragma unroll 1
    for (int xb = 0; xb < 84; xb += 3) {
#pragma unroll
        for (int k = 0; k < 3; ++k) {
            const int x = xb + k;
            const int xn = x + 1;
            const bool cok = xn < 84;
#pragma unroll
            for (int i = 0; i < 3; ++i)
#pragma unroll
                for (int r = 0; r < 4; ++r) {
                    const int ry = 2 * wy - 1 + r;
                    hw[i][r][(k + 1) % 3] = (cok && (unsigned)ry < 84u)
                        ? xT[((size_t)i * 7056 + ry * 84 + xn) * 128 + s] : 0.f;
                }
            const int wx = x >> 1;
            const int xbit = x & 1;
            float u[2][2];
#pragma unroll
            for (int oo = 0; oo < 2; ++oo) {
                const size_t base = ((size_t)(cellrow + wx) * 64 + o0 + oo) * 128 + s;
                const int mv = m1[base];
                const float gv = g1[base];
                u[oo][0] = (mv == (4 | 0 | xbit)) ? gv : 0.f;   // dense row even
                u[oo][1] = (mv == (4 | 2 | xbit)) ? gv : 0.f;   // dense row odd
            }
#pragma unroll
            for (int oo = 0; oo < 2; ++oo)
#pragma unroll
                for (int yy = 0; yy < 2; ++yy)
#pragma unroll
                    for (int i = 0; i < 3; ++i)
#pragma unroll
                        for (int dy = 0; dy < 3; ++dy)
#pragma unroll
                            for (int dx = 0; dx < 3; ++dx)
                                acc[oo][i][dy * 3 + dx] =
                                    fmaf(u[oo][yy], hw[i][yy + dy][(k + dx + 2) % 3],
                                         acc[oo][i][dy * 3 + dx]);
        }
    }
    const float sc = scal_[0];
#pragma unroll
    for (int oo = 0; oo < 2; ++oo)
#pragma unroll
        for (int i = 0; i < 3; ++i)
#pragma unroll
            for (int t = 0; t < 9; ++t)
                atomicAdd(&JT[(size_t)(OFF_W1 + (o0 + oo) * 27 + i * 9 + t) * 128 + s],
                          sc * acc[oo][i][t]);
}

// ---------------- bias grads: partials then reduce ----------------
__global__ __launch_bounds__(128) void k_dbpart(
    const float* __restrict__ g1, const float* __restrict__ g2,
    const float* __restrict__ g3, const float* __restrict__ g4,
    const unsigned char* __restrict__ m1, const unsigned char* __restrict__ m2,
    const unsigned char* __restrict__ m3, const unsigned char* __restrict__ m4,
    float* __restrict__ part)
{
    const int s = threadIdx.x;
    const int o = blockIdx.x, chunk = blockIdx.y, layer = blockIdx.z;
    const float* g; const unsigned char* m; int nc;
    if (layer == 0)      { g = g1; m = m1; nc = 1764; }
    else if (layer == 1) { g = g2; m = m2; nc = 441; }
    else if (layer == 2) { g = g3; m = m3; nc = 100; }
    else                 { g = g4; m = m4; nc = 25; }
    const int c0 = chunk * nc / 4, c1 = (chunk + 1) * nc / 4;
    float acc = 0.f;
    for (int cell = c0; cell < c1; ++cell) {
        const size_t base = ((size_t)cell * 64 + o) * 128 + s;
        acc += (m[base] & 4) ? g[base] : 0.f;
    }
    part[((size_t)(layer * 4 + chunk) * 64 + o) * 128 + s] = acc;
}

__global__ __launch_bounds__(256) void k_dbred(
    const float* __restrict__ part, const float* __restrict__ scal_,
    float* __restrict__ JT)
{
    const int idx = blockIdx.x * 256 + threadIdx.x;   // 4*64*128
    const int layer = idx >> 13, o = (idx >> 7) & 63, s = idx & 127;
    float v = 0.f;
#pragma unroll
    for (int ch = 0; ch < 4; ++ch)
        v += part[((size_t)(layer * 4 + ch) * 64 + o) * 128 + s];
    const int offb[4] = {OFF_B1, OFF_B2, OFF_B3, OFF_B4};
    JT[(size_t)(offb[layer] + o) * 128 + s] = scal_[2 * layer + 1] * v;
}

// ---------------- NTK GEMM: per-block partials, then reduce (+fc_b const) ----------------
constexpr int NTK_BLOCKS = 446;   // 446 * 8 * 32 = 114176 = PJ
__global__ __launch_bounds__(256) void k_ntk(const float* __restrict__ JT,
                                             float* __restrict__ part)
{
    __shared__ float As[32][64], Bs[32][64];
    const int tx = threadIdx.x, ty = threadIdx.y;
    const int t = ty * 16 + tx;
    float acc[4][4];
#pragma unroll
    for (int a = 0; a < 4; ++a)
#pragma unroll
        for (int b = 0; b < 4; ++b) acc[a][b] = 0.f;

    for (int ch = 0; ch < 8; ++ch) {
        const int k0 = (blockIdx.x * 8 + ch) * 32;
        __syncthreads();
#pragma unroll
        for (int q = 0; q < 4; ++q) {
            const int fidx = q * 256 + t;          // float4 index within [32][128]
            const int row = fidx >> 5;
            const int c4 = (fidx & 31) * 4;
            const float4 v = *(const float4*)&JT[(size_t)(k0 + row) * 128 + c4];
            if (c4 < 64) *(float4*)&As[row][c4] = v;
            else         *(float4*)&Bs[row][c4 - 64] = v;
        }
        __syncthreads();
#pragma unroll
        for (int k = 0; k < 32; ++k) {
            const float4 av = *(const float4*)&As[k][ty * 4];
            const float4 bv = *(const float4*)&Bs[k][tx * 4];
            acc[0][0] = fmaf(av.x, bv.x, acc[0][0]);
            acc[0][1] = fmaf(av.x, bv.y, acc[0][1]);
            acc[0][2] = fmaf(av.x, bv.z, acc[0][2]);
            acc[0][3] = fmaf(av.x, bv.w, acc[0][3]);
            acc[1][0] = fmaf(av.y, bv.x, acc[1][0]);
            acc[1][1] = fmaf(av.y, bv.y, acc[1][1]);
            acc[1][2] = fmaf(av.y, bv.z, acc[1][2]);
            acc[1][3] = fmaf(av.y, bv.w, acc[1][3]);
            acc[2][0] = fmaf(av.z, bv.x, acc[2][0]);
            acc[2][1] = fmaf(av.z, bv.y, acc[2][1]);
            acc[2][2] = fmaf(av.z, bv.z, acc[2][2]);
            acc[2][3] = fmaf(av.z, bv.w, acc[2][3]);
            acc[3][0] = fmaf(av.w, bv.x, acc[3][0]);
            acc[3][1] = fmaf(av.w, bv.y, acc[3][1]);
            acc[3][2] = fmaf(av.w, bv.z, acc[3][2]);
            acc[3][3] = fmaf(av.w, bv.w, acc[3][3]);
        }
    }
#pragma unroll
    for (int a = 0; a < 4; ++a)
#pragma unroll
        for (int b = 0; b < 4; ++b)
            part[(size_t)blockIdx.x * 4096 + (ty * 4 + a) * 64 + (tx * 4 + b)] = acc[a][b];
}

__global__ __launch_bounds__(256) void k_ntkred(
    const float* __restrict__ part, const float* __restrict__ scal_,
    float* __restrict__ out)
{
    const int t = blockIdx.x * 256 + threadIdx.x;   // 4096
    float v = scal_[9] * scal_[9];
    for (int ck = 0; ck < NTK_BLOCKS; ++ck) v += part[(size_t)ck * 4096 + t];
    out[t] = v;
}

// ---------------- host launch ----------------
extern "C" void kernel_launch(void* const* d_in, const int* in_sizes, int n_in,
                              void* d_out, int out_size, void* d_ws, size_t ws_size,
                              hipStream_t stream)
{
    const void* IN[14];
    if (n_in >= 14 && in_sizes[2] == 10 && in_sizes[3] == 1) {
        for (int k = 0; k < 14; ++k) IN[k] = d_in[k];
    } else {
        IN[0] = d_in[0]; IN[1] = d_in[1];
        IN[2] = d_in[12]; IN[3] = d_in[13];
        for (int k = 0; k < 8; ++k) IN[4 + k] = d_in[2 + k];
        IN[12] = d_in[10]; IN[13] = d_in[11];
    }
    const float* x1   = (const float*)IN[0];
    const float* x2   = (const float*)IN[1];
    const float* scal = (const float*)IN[2];
    const int*   cp   = (const int*)IN[3];
    const float* w1 = (const float*)IN[4];  const float* b1 = (const float*)IN[5];
    const float* w2 = (const float*)IN[6];  const float* b2 = (const float*)IN[7];
    const float* w3 = (const float*)IN[8];  const float* b3 = (const float*)IN[9];
    const float* w4 = (const float*)IN[10]; const float* b4 = (const float*)IN[11];
    const float* fcw = (const float*)IN[12];
    float* out = (float*)d_out;

    char* base = (char*)d_ws;
    size_t off = 0;
    auto alloc = [&](size_t bytes) -> char* {
        char* p = base + off;
        off = (off + bytes + 255) & ~(size_t)255;
        return p;
    };
    // JT first. xT (10.84 MB) aliases JT's W3 segment (features 38720..59888,
    // inside W3 [38720,75584)): xT consumers are k_fwd<3,84> and k_wgrad1; after
    // k_wgrad1, W3 is memset to 0 and k_wgrad<10,21> atomically accumulates it.
    // W1/B1/W2 (head memset) and W4 (second head memset) do not overlap xT.
    float* JT = (float*)alloc((size_t)PJ * 128 * 4);      // 58.5 MB
    float* xT = JT + (size_t)OFF_W3 * 128;
    float* p1 = (float*)alloc((size_t)1764 * 64 * 128 * 4);
    float* p2 = (float*)alloc((size_t)441  * 64 * 128 * 4);
    float* p3 = (float*)alloc((size_t)100  * 64 * 128 * 4);
    float* p4 = (float*)alloc((size_t)25   * 64 * 128 * 4);
    unsigned char* m1 = (unsigned char*)alloc((size_t)1764 * 64 * 128);
    unsigned char* m2 = (unsigned char*)alloc((size_t)441  * 64 * 128);
    unsigned char* m3 = (unsigned char*)alloc((size_t)100  * 64 * 128);
    unsigned char* m4 = (unsigned char*)alloc((size_t)25   * 64 * 128);
    float* g1 = (float*)alloc((size_t)1764 * 64 * 128 * 4);
    float* g2 = (float*)alloc((size_t)441  * 64 * 128 * 4);
    float* g3 = (float*)alloc((size_t)100  * 64 * 128 * 4);
    float* g4 = (float*)alloc((size_t)25   * 64 * 128 * 4);
    float* wS1 = (float*)alloc(1728 * 4);
    float* wS2 = (float*)alloc(36864 * 4);
    float* wS3 = (float*)alloc(36864 * 4);
    float* wS4 = (float*)alloc(36864 * 4);
    float* wB2 = (float*)alloc(36864 * 4);
    float* wB3 = (float*)alloc(36864 * 4);
    float* wB4 = (float*)alloc(36864 * 4);
    float* dbp = (float*)alloc((size_t)16 * 64 * 128 * 4);
    // NTK partials (446*16KB = 7.3 MB) alias g1 (57.8 MB): g1 dead after k_dbpart.
    float* ntkp = g1;
    (void)ws_size;

    // ---- zero atomic-accumulated segments: W1+B1+W2 and W4 ----
    hipMemsetAsync(JT, 0, (size_t)OFF_B2 * 128 * 4, stream);
    hipMemsetAsync(JT + (size_t)OFF_W4 * 128, 0, (size_t)36864 * 128 * 4, stream);

    // ---- prep ----
    k_transpose<<<dim3(662, 4), dim3(32, 8), 0, stream>>>(x1, x2, xT);
    k_wprep<<<144, 256, 0, stream>>>(w1, w2, w3, w4, wS1, wS2, wS3, wS4, wB2, wB3, wB4);

    // ---- forward (xT: [3][84][84][128]; p_l: [y][x][64][128]) ----
    k_fwd<3, 84, 8, 84 * 84 * 128, 84 * 128, 128>
        <<<dim3(21, 8, 21), dim3(128, 2), 0, stream>>>(xT, wS1, b1, p1, m1);
    k_fwd<64, 42, 8, 128, 42 * 64 * 128, 64 * 128>
        <<<dim3(11, 8, 11), dim3(128, 2), 0, stream>>>(p1, wS2, b2, p2, m2);
    k_fwd<64, 21, 4, 128, 21 * 64 * 128, 64 * 128>
        <<<dim3(5, 16, 5), dim3(128, 2), 0, stream>>>(p2, wS3, b3, p3, m3);
    k_fwd<64, 10, 4, 128, 10 * 64 * 128, 64 * 128>
        <<<dim3(3, 16, 3), dim3(128, 2), 0, stream>>>(p3, wS4, b4, p4, m4);

    // ---- seed gamma4 + h segment ----
    k_seed<<<1600, 128, 0, stream>>>(fcw, cp, p4, scal, g4, JT);

    // ---- backward cotangents (dense, routing inline) ----
    k_bwd<5, 10, 8><<<dim3(3, 8, 5),  dim3(128, 2), 0, stream>>>(g4, m4, wB4, g3);
    k_bwd<10, 21, 8><<<dim3(6, 8, 11), dim3(128, 2), 0, stream>>>(g3, m3, wB3, g2);
    k_bwd<21, 42, 8><<<dim3(11, 8, 21), dim3(128, 2), 0, stream>>>(g2, m2, wB2, g1);

    // ---- weight grads (round-6 form; deeper z-split for occupancy) ----
    k_wgrad<5, 10><<<dim3(32, 32, 2), 128, 0, stream>>>(g4, m4, p3, scal, 6, OFF_W4, JT, 5);
    k_wgrad1<<<dim3(32, 42), 128, 0, stream>>>(g1, m1, xT, scal, JT);
    // xT retired; zero W3 then accumulate it
    hipMemsetAsync(JT + (size_t)OFF_W3 * 128, 0, (size_t)36864 * 128 * 4, stream);
    k_wgrad<10, 21><<<dim3(32, 32, 3), 128, 0, stream>>>(g3, m3, p2, scal, 4, OFF_W3, JT, 7);
    k_wgrad<21, 42><<<dim3(32, 32, 6), 128, 0, stream>>>(g2, m2, p1, scal, 2, OFF_W2, JT, 7);

    // ---- bias grads ----
    k_dbpart<<<dim3(64, 4, 4), 128, 0, stream>>>(g1, g2, g3, g4, m1, m2, m3, m4, dbp);
    k_dbred<<<128, 256, 0, stream>>>(dbp, scal, JT);

    // ---- K = JT1^T . JT2 + s_fcb^2 (ntkp aliases g1; g1 dead after dbpart) ----
    k_ntk<<<NTK_BLOCKS, dim3(16, 16), 0, stream>>>(JT, ntkp);
    k_ntkred<<<16, 256, 0, stream>>>(ntkp, scal, out);
}

// Round 9
// 2262.711 us; speedup vs baseline: 1.2924x; 1.0756x over previous
//
#include <hip/hip_runtime.h>
#include <cstdint>

// ---------------- problem constants ----------------
// S=128 samples (64 x1 + 64 x2) live in the lane dimension of every tensor:
// activations/cotangents/masks are [y][x][ch][s=128] ("CHWN"-style, s innermost).
constexpr int OFF_W1 = 0;        // 64*3*9
constexpr int OFF_B1 = 1728;
constexpr int OFF_W2 = 1792;     // 64*64*9
constexpr int OFF_B2 = 38656;
constexpr int OFF_W3 = 38720;
constexpr int OFF_B3 = 75584;
constexpr int OFF_W4 = 75648;
constexpr int OFF_B4 = 112512;
constexpr int OFF_H  = 112576;   // 1600
constexpr int PJ     = 114176;   // = 223*512

// ---------------- input transpose: [128][3*84*84] -> [3*84*84][128] ----------------
__global__ __launch_bounds__(256) void k_transpose(
    const float* __restrict__ x1, const float* __restrict__ x2, float* __restrict__ xT)
{
    __shared__ float tile[32][33];
    const int c0 = blockIdx.x * 32, s0 = blockIdx.y * 32;
    const int tx = threadIdx.x, ty = threadIdx.y;
#pragma unroll
    for (int k = 0; k < 4; ++k) {
        const int row = s0 + ty + k * 8;          // sample
        const int col = c0 + tx;                  // flat (i,y,x)
        const float* src = (row < 64) ? (x1 + (size_t)row * 21168)
                                      : (x2 + (size_t)(row - 64) * 21168);
        tile[ty + k * 8][tx] = (col < 21168) ? src[col] : 0.f;
    }
    __syncthreads();
#pragma unroll
    for (int k = 0; k < 4; ++k) {
        const int c = c0 + ty + k * 8;
        if (c < 21168) xT[(size_t)c * 128 + (s0 + tx)] = tile[tx][ty + k * 8];
    }
}

// ---------------- weight prep ----------------
// wS_l[i][t][o] = w_l[o][i][t]      (forward, scalar-load friendly)
// wB_l[o][t][i] = w_l[o][i][8-t]    (backward conv-transpose)
__global__ __launch_bounds__(256) void k_wprep(
    const float* __restrict__ w1, const float* __restrict__ w2,
    const float* __restrict__ w3, const float* __restrict__ w4,
    float* __restrict__ wS1, float* __restrict__ wS2, float* __restrict__ wS3,
    float* __restrict__ wS4, float* __restrict__ wB2, float* __restrict__ wB3,
    float* __restrict__ wB4)
{
    const int idx = blockIdx.x * 256 + threadIdx.x;
    if (idx >= 36864) return;
    const int o = idx / 576, rem = idx % 576, i = rem / 9, t = rem % 9;
    wS2[(i * 9 + t) * 64 + o] = w2[idx];
    wS3[(i * 9 + t) * 64 + o] = w3[idx];
    wS4[(i * 9 + t) * 64 + o] = w4[idx];
    wB2[(o * 9 + (8 - t)) * 64 + i] = w2[idx];
    wB3[(o * 9 + (8 - t)) * 64 + i] = w3[idx];
    wB4[(o * 9 + (8 - t)) * 64 + i] = w4[idx];
    if (idx < 1728) {
        const int o1 = idx / 27, r1 = idx % 27, i1 = r1 / 9, t1 = r1 % 9;
        wS1[(i1 * 9 + t1) * 64 + o1] = w1[idx];
    }
}

// ---------------- forward conv3x3(SAME)+bias+relu+maxpool2x2, fused ----------------
// block (128 s-lanes, 2): ty = pooled row within pair. Each thread: OB o's x 2 conv rows x 4 conv cols.
// in strides (floats): i*SI + y*SY + x*SX + lane
template<int CIN, int TIN, int OB, int SI, int SY, int SX>
__global__ __launch_bounds__(256) void k_fwd(
    const float* __restrict__ in, const float* __restrict__ wS,
    const float* __restrict__ bias, float* __restrict__ pout,
    unsigned char* __restrict__ mout)
{
    constexpr int PW = TIN / 2;
    const int lane = threadIdx.x;
    const int x0 = blockIdx.x * 4;
    const int o0 = blockIdx.y * OB;
    const int pr = blockIdx.z * 2 + threadIdx.y;
    if (pr >= PW) return;
    const int cr0 = 2 * pr;

    float acc[OB][2][4];
#pragma unroll
    for (int j = 0; j < OB; ++j)
#pragma unroll
        for (int r = 0; r < 2; ++r)
#pragma unroll
            for (int p = 0; p < 4; ++p) acc[j][r][p] = 0.f;

#pragma unroll 1
    for (int i = 0; i < CIN; ++i) {
        float a[4][6];
#pragma unroll
        for (int rr = 0; rr < 4; ++rr) {
            const int y = cr0 - 1 + rr;
            const bool rok = (unsigned)y < (unsigned)TIN;
#pragma unroll
            for (int cc = 0; cc < 6; ++cc) {
                const int x = x0 - 1 + cc;
                a[rr][cc] = (rok && (unsigned)x < (unsigned)TIN)
                    ? in[(size_t)i * SI + (size_t)y * SY + (size_t)x * SX + lane] : 0.f;
            }
        }
        const float* wrow = wS + (i * 9) * 64 + o0;   // uniform -> s_load
#pragma unroll
        for (int t = 0; t < 9; ++t) {
            const int dy = t / 3, dx = t % 3;
#pragma unroll
            for (int j = 0; j < OB; ++j) {
                const float wv = wrow[t * 64 + j];
#pragma unroll
                for (int r = 0; r < 2; ++r)
#pragma unroll
                    for (int p = 0; p < 4; ++p)
                        acc[j][r][p] = fmaf(wv, a[r + dy][p + dx], acc[j][r][p]);
            }
        }
    }
#pragma unroll
    for (int j = 0; j < OB; ++j) {
        const float b = bias[o0 + j];
#pragma unroll
        for (int q = 0; q < 2; ++q) {
            const int wx = x0 / 2 + q;
            if (wx >= PW) continue;
            const float c00 = fmaxf(acc[j][0][2 * q]     + b, 0.f);
            const float c01 = fmaxf(acc[j][0][2 * q + 1] + b, 0.f);
            const float c10 = fmaxf(acc[j][1][2 * q]     + b, 0.f);
            const float c11 = fmaxf(acc[j][1][2 * q + 1] + b, 0.f);
            float best = c00; int idx = 0;                     // first-strict-max (matches XLA)
            if (c01 > best) { best = c01; idx = 1; }
            if (c10 > best) { best = c10; idx = 2; }
            if (c11 > best) { best = c11; idx = 3; }
            const size_t oi = ((size_t)(pr * PW + wx) * 64 + (o0 + j)) * 128 + lane;
            pout[oi] = best;
            mout[oi] = (unsigned char)(idx | (best > 0.f ? 4 : 0));
        }
    }
}

// ---------------- seed: gamma4 = fc_w[c] reshaped [64][5][5]; J h-segment ----------------
__global__ __launch_bounds__(128) void k_seed(
    const float* __restrict__ fcw, const int* __restrict__ cptr,
    const float* __restrict__ p4, const float* __restrict__ scal_,
    float* __restrict__ g4, float* __restrict__ JT)
{
    const int s = threadIdx.x;
    const int cell = blockIdx.x / 64, o = blockIdx.x % 64;
    const int c = *cptr;
    const int j = o * 25 + cell;                   // CHW flatten of [64][5][5]
    const size_t base = ((size_t)cell * 64 + o) * 128 + s;
    g4[base] = fcw[(size_t)c * 1600 + j];
    JT[(size_t)(OFF_H + j) * 128 + s] = scal_[8] * p4[base];
}

// ---------------- backward: gamma_{l-1} = convT(w_l, u_l), u routed inline ----------------
// gl/ml on TL^2 pooled grid; output dense on TP^2 grid. u_l[y][x][o] = (m==code)?g:0.
// Dedup: the 3x6 dense window touches only 2x4 pooled cells; load those once per o
// (wave-uniform scalar addressing) and route in registers via static selectors.
template<int TL, int TP, int OB>
__global__ __launch_bounds__(256) void k_bwd(
    const float* __restrict__ gl, const unsigned char* __restrict__ ml,
    const float* __restrict__ wB, float* __restrict__ gout)
{
    const int lane = threadIdx.x;
    const int x0 = blockIdx.x * 4;
    const int i0 = blockIdx.y * OB;
    const int row = blockIdx.z * 2 + threadIdx.y;
    if (row >= TP) return;

    // pooled window: rows prA=(row-1)>>1, prB=(row+1)>>1; cols pc0..pc0+3
    const int prA = (row - 1) >> 1;
    const int prB = (row + 1) >> 1;
    const int pc0 = (x0 - 1) >> 1;
    const int rpar = row & 1;
    // rr -> pooled-row slot: rr=0 -> A, rr=1 -> (rpar? A : B), rr=2 -> B
    const int ridx1 = rpar ? 0 : 1;

    float acc[OB][4];
#pragma unroll
    for (int j = 0; j < OB; ++j)
#pragma unroll
        for (int p = 0; p < 4; ++p) acc[j][p] = 0.f;

#pragma unroll 1
    for (int o = 0; o < 64; ++o) {
        // load the 2x4 pooled (mask, gamma) window; invalid cells never match
        int   mv[2][4];
        float gv[2][4];
#pragma unroll
        for (int r2 = 0; r2 < 2; ++r2) {
            const int prr = r2 ? prB : prA;
            const bool rok = (unsigned)prr < (unsigned)TL;
#pragma unroll
            for (int c2 = 0; c2 < 4; ++c2) {
                const int pcc = pc0 + c2;
                const bool ok = rok && (unsigned)pcc < (unsigned)TL;
                if (ok) {
                    const size_t base = ((size_t)(prr * TL + pcc) * 64 + o) * 128 + lane;
                    mv[r2][c2] = ml[base];
                    gv[r2][c2] = gl[base];
                } else {
                    mv[r2][c2] = 255;
                    gv[r2][c2] = 0.f;
                }
            }
        }
        // route into the 3x6 dense window
        float a[3][6];
#pragma unroll
        for (int rr = 0; rr < 3; ++rr) {
            const int ridx = (rr == 0) ? 0 : ((rr == 2) ? 1 : ridx1);
            const int ycode = 4 | (((row - 1 + rr) & 1) << 1);
#pragma unroll
            for (int cc = 0; cc < 6; ++cc) {
                const int cidx = (cc + 1) >> 1;          // {0,1,1,2,2,3}
                const int code = ycode | ((cc + 1) & 1); // x0 even -> x parity = (cc+1)&1
                a[rr][cc] = (mv[ridx][cidx] == code) ? gv[ridx][cidx] : 0.f;
            }
        }
        const float* wrow = wB + (o * 9) * 64 + i0;   // uniform -> s_load
#pragma unroll
        for (int t = 0; t < 9; ++t) {
            const int dy = t / 3, dx = t % 3;
#pragma unroll
            for (int j = 0; j < OB; ++j) {
                const float wv = wrow[t * 64 + j];
#pragma unroll
                for (int p = 0; p < 4; ++p)
                    acc[j][p] = fmaf(wv, a[dy][p + dx], acc[j][p]);
            }
        }
    }
#pragma unroll
    for (int j = 0; j < OB; ++j)
#pragma unroll
        for (int p = 0; p < 4; ++p) {
            const int x = x0 + p;
            if (x < TP)
                gout[((size_t)(row * TP + x) * 64 + (i0 + j)) * 128 + lane] = acc[j][p];
        }
}

// ---------------- weight grads (layers 2..4): dW[o,i,t] = sum_z u[z][o]*h[z+t-1][i] ----------------
// u routed inline from (gl,ml) on TL^2; h on TIN^2. Per thread: 2o x 2i x 9 acc, lane = s.
// Round-6 form (44 VGPR); occupancy raised via dense-row z-split (atomic into
// pre-zeroed segments). 152-VGPR pooled-cell variant regressed (round 7).
template<int TL, int TIN>
__global__ __launch_bounds__(128) void k_wgrad(
    const float* __restrict__ gl, const unsigned char* __restrict__ ml,
    const float* __restrict__ h, const float* __restrict__ scal_,
    const int scalIdx, const int joff, float* __restrict__ JT, const int ychunk)
{
    const int s = threadIdx.x;
    const int o0 = blockIdx.x * 2, i0 = blockIdx.y * 2;
    const int y0 = blockIdx.z * ychunk;
    const int y1 = (y0 + ychunk < TIN) ? y0 + ychunk : TIN;

    float acc[2][2][9];
#pragma unroll
    for (int a = 0; a < 2; ++a)
#pragma unroll
        for (int b = 0; b < 2; ++b)
#pragma unroll
            for (int t = 0; t < 9; ++t) acc[a][b][t] = 0.f;

#pragma unroll 1
    for (int y = y0; y < y1; ++y) {
        const int wy = y >> 1;
        const int ybit = (y & 1) << 1;
        float hw[2][3][3];                       // [i][dy][col%3] rotating window
#pragma unroll
        for (int ji = 0; ji < 2; ++ji)
#pragma unroll
            for (int dy = 0; dy < 3; ++dy) {
                const int ry = y + dy - 1;
                const bool rok = (unsigned)ry < (unsigned)TIN;
                hw[ji][dy][2] = 0.f;             // col -1
                hw[ji][dy][1] = 0.f;
                hw[ji][dy][0] = rok ? h[((size_t)(ry * TIN) * 64 + i0 + ji) * 128 + s] : 0.f;
            }
#pragma unroll 1
        for (int xb = 0; xb < ((TIN + 2) / 3) * 3; xb += 3) {
#pragma unroll
            for (int k = 0; k < 3; ++k) {
                const int x = xb + k;
                const int xn = x + 1;
                const bool cok = xn < TIN;
#pragma unroll
                for (int ji = 0; ji < 2; ++ji)
#pragma unroll
                    for (int dy = 0; dy < 3; ++dy) {
                        const int ry = y + dy - 1;
                        hw[ji][dy][(k + 1) % 3] =
                            (cok && (unsigned)ry < (unsigned)TIN)
                                ? h[((size_t)(ry * TIN + xn) * 64 + i0 + ji) * 128 + s] : 0.f;
                    }
                if (x < TIN) {
                    const int wx = x >> 1;
                    const bool uok = (wy < TL) && (wx < TL);
                    const int code = 4 | ybit | (x & 1);
                    float u[2] = {0.f, 0.f};
                    if (uok) {
#pragma unroll
                        for (int jo = 0; jo < 2; ++jo) {
                            const size_t base = ((size_t)(wy * TL + wx) * 64 + o0 + jo) * 128 + s;
                            const int mv = ml[base];
                            const float gv = gl[base];
                            u[jo] = (mv == code) ? gv : 0.f;
                        }
                    }
#pragma unroll
                    for (int jo = 0; jo < 2; ++jo)
#pragma unroll
                        for (int ji = 0; ji < 2; ++ji)
#pragma unroll
                            for (int dy = 0; dy < 3; ++dy)
#pragma unroll
                                for (int dx = 0; dx < 3; ++dx)
                                    acc[jo][ji][dy * 3 + dx] =
                                        fmaf(u[jo], hw[ji][dy][(k + dx + 2) % 3],
                                             acc[jo][ji][dy * 3 + dx]);
                }
            }
        }
    }
    const float sc = scal_[scalIdx];
#pragma unroll
    for (int jo = 0; jo < 2; ++jo)
#pragma unroll
        for (int ji = 0; ji < 2; ++ji)
#pragma unroll
            for (int t = 0; t < 9; ++t) {
                const int feat = joff + ((o0 + jo) * 64 + (i0 + ji)) * 9 + t;
                atomicAdd(&JT[(size_t)feat * 128 + s], sc * acc[jo][ji][t]);
            }
}

// ---------------- weight grad layer 1: dense-routed u, lane=s, coalesced ----------------
// grid: (32 o-pairs, 42 pooled rows wy), block 128. Covers dense rows y=2wy, 2wy+1.
// Atomic split over wy into pre-zeroed W1 segment of JT. xT: [3][84][84][128].
__global__ __launch_bounds__(128) void k_wgrad1(
    const float* __restrict__ g1, const unsigned char* __restrict__ m1,
    const float* __restrict__ xT, const float* __restrict__ scal_,
    float* __restrict__ JT)
{
    const int s = threadIdx.x;
    const int o0 = blockIdx.x * 2;
    const int wy = blockIdx.y;

    float acc[2][3][9];
#pragma unroll
    for (int oo = 0; oo < 2; ++oo)
#pragma unroll
        for (int i = 0; i < 3; ++i)
#pragma unroll
            for (int t = 0; t < 9; ++t) acc[oo][i][t] = 0.f;

    // window rows ry = 2wy-1 .. 2wy+2 ; rotating col window idx (k+dx+2)%3
    float hw[3][4][3];
#pragma unroll
    for (int i = 0; i < 3; ++i)
#pragma unroll
        for (int r = 0; r < 4; ++r) {
            const int ry = 2 * wy - 1 + r;
            hw[i][r][2] = 0.f;   // col -1
            hw[i][r][1] = 0.f;
            hw[i][r][0] = ((unsigned)ry < 84u)
                ? xT[((size_t)i * 7056 + ry * 84) * 128 + s] : 0.f;  // col 0
        }
    const int cellrow = wy * 42;

#pragma unroll 1
    for (int xb = 0; xb < 84; xb += 3) {
#pragma unroll
        for (int k = 0; k < 3; ++k) {
            const int x = xb + k;
            const int xn = x + 1;
            const bool cok = xn < 84;
#pragma unroll
            for (int i = 0; i < 3; ++i)
#pragma unroll
                for (int r = 0; r < 4; ++r) {
                    const int ry = 2 * wy - 1 + r;
                    hw[i][r][(k + 1) % 3] = (cok && (unsigned)ry < 84u)
                        ? xT[((size_t)i * 7056 + ry * 84 + xn) * 128 + s] : 0.f;
                }
            const int wx = x >> 1;
            const int xbit = x & 1;
            float u[2][2];
#pragma unroll
            for (int oo = 0; oo < 2; ++oo) {
                const size_t base = ((size_t)(cellrow + wx) * 64 + o0 + oo) * 128 + s;
                const int mv = m1[base];
                const float gv = g1[base];
                u[oo][0] = (mv == (4 | 0 | xbit)) ? gv : 0.f;   // dense row even
                u[oo][1] = (mv == (4 | 2 | xbit)) ? gv : 0.f;   // dense row odd
            }
#pragma unroll
            for (int oo = 0; oo < 2; ++oo)
#pragma unroll
                for (int yy = 0; yy < 2; ++yy)
#pragma unroll
                    for (int i = 0; i < 3; ++i)
#pragma unroll
                        for (int dy = 0; dy < 3; ++dy)
#pragma unroll
                            for (int dx = 0; dx < 3; ++dx)
                                acc[oo][i][dy * 3 + dx] =
                                    fmaf(u[oo][yy], hw[i][yy + dy][(k + dx + 2) % 3],
                                         acc[oo][i][dy * 3 + dx]);
        }
    }
    const float sc = scal_[0];
#pragma unroll
    for (int oo = 0; oo < 2; ++oo)
#pragma unroll
        for (int i = 0; i < 3; ++i)
#pragma unroll
            for (int t = 0; t < 9; ++t)
                atomicAdd(&JT[(size_t)(OFF_W1 + (o0 + oo) * 27 + i * 9 + t) * 128 + s],
                          sc * acc[oo][i][t]);
}

// ---------------- bias grads: partials then reduce ----------------
__global__ __launch_bounds__(128) void k_dbpart(
    const float* __restrict__ g1, const float* __restrict__ g2,
    const float* __restrict__ g3, const float* __restrict__ g4,
    const unsigned char* __restrict__ m1, const unsigned char* __restrict__ m2,
    const unsigned char* __restrict__ m3, const unsigned char* __restrict__ m4,
    float* __restrict__ part)
{
    const int s = threadIdx.x;
    const int o = blockIdx.x, chunk = blockIdx.y, layer = blockIdx.z;
    const float* g; const unsigned char* m; int nc;
    if (layer == 0)      { g = g1; m = m1; nc = 1764; }
    else if (layer == 1) { g = g2; m = m2; nc = 441; }
    else if (layer == 2) { g = g3; m = m3; nc = 100; }
    else                 { g = g4; m = m4; nc = 25; }
    const int c0 = chunk * nc / 4, c1 = (chunk + 1) * nc / 4;
    float acc = 0.f;
    for (int cell = c0; cell < c1; ++cell) {
        const size_t base = ((size_t)cell * 64 + o) * 128 + s;
        acc += (m[base] & 4) ? g[base] : 0.f;
    }
    part[((size_t)(layer * 4 + chunk) * 64 + o) * 128 + s] = acc;
}

__global__ __launch_bounds__(256) void k_dbred(
    const float* __restrict__ part, const float* __restrict__ scal_,
    float* __restrict__ JT)
{
    const int idx = blockIdx.x * 256 + threadIdx.x;   // 4*64*128
    const int layer = idx >> 13, o = (idx >> 7) & 63, s = idx & 127;
    float v = 0.f;
#pragma unroll
    for (int ch = 0; ch < 4; ++ch)
        v += part[((size_t)(layer * 4 + ch) * 64 + o) * 128 + s];
    const int offb[4] = {OFF_B1, OFF_B2, OFF_B3, OFF_B4};
    JT[(size_t)(offb[layer] + o) * 128 + s] = scal_[2 * layer + 1] * v;
}

// ---------------- NTK GEMM: per-block partials, then reduce (+fc_b const) ----------------
constexpr int NTK_BLOCKS = 446;   // 446 * 8 * 32 = 114176 = PJ
__global__ __launch_bounds__(256) void k_ntk(const float* __restrict__ JT,
                                             float* __restrict__ part)
{
    __shared__ float As[32][64], Bs[32][64];
    const int tx = threadIdx.x, ty = threadIdx.y;
    const int t = ty * 16 + tx;
    float acc[4][4];
#pragma unroll
    for (int a = 0; a < 4; ++a)
#pragma unroll
        for (int b = 0; b < 4; ++b) acc[a][b] = 0.f;

    for (int ch = 0; ch < 8; ++ch) {
        const int k0 = (blockIdx.x * 8 + ch) * 32;
        __syncthreads();
#pragma unroll
        for (int q = 0; q < 4; ++q) {
            const int fidx = q * 256 + t;          // float4 index within [32][128]
            const int row = fidx >> 5;
            const int c4 = (fidx & 31) * 4;
            const float4 v = *(const float4*)&JT[(size_t)(k0 + row) * 128 + c4];
            if (c4 < 64) *(float4*)&As[row][c4] = v;
            else         *(float4*)&Bs[row][c4 - 64] = v;
        }
        __syncthreads();
#pragma unroll
        for (int k = 0; k < 32; ++k) {
            const float4 av = *(const float4*)&As[k][ty * 4];
            const float4 bv = *(const float4*)&Bs[k][tx * 4];
            acc[0][0] = fmaf(av.x, bv.x, acc[0][0]);
            acc[0][1] = fmaf(av.x, bv.y, acc[0][1]);
            acc[0][2] = fmaf(av.x, bv.z, acc[0][2]);
            acc[0][3] = fmaf(av.x, bv.w, acc[0][3]);
            acc[1][0] = fmaf(av.y, bv.x, acc[1][0]);
            acc[1][1] = fmaf(av.y, bv.y, acc[1][1]);
            acc[1][2] = fmaf(av.y, bv.z, acc[1][2]);
            acc[1][3] = fmaf(av.y, bv.w, acc[1][3]);
            acc[2][0] = fmaf(av.z, bv.x, acc[2][0]);
            acc[2][1] = fmaf(av.z, bv.y, acc[2][1]);
            acc[2][2] = fmaf(av.z, bv.z, acc[2][2]);
            acc[2][3] = fmaf(av.z, bv.w, acc[2][3]);
            acc[3][0] = fmaf(av.w, bv.x, acc[3][0]);
            acc[3][1] = fmaf(av.w, bv.y, acc[3][1]);
            acc[3][2] = fmaf(av.w, bv.z, acc[3][2]);
            acc[3][3] = fmaf(av.w, bv.w, acc[3][3]);
        }
    }
#pragma unroll
    for (int a = 0; a < 4; ++a)
#pragma unroll
        for (int b = 0; b < 4; ++b)
            part[(size_t)blockIdx.x * 4096 + (ty * 4 + a) * 64 + (tx * 4 + b)] = acc[a][b];
}

__global__ __launch_bounds__(256) void k_ntkred(
    const float* __restrict__ part, const float* __restrict__ scal_,
    float* __restrict__ out)
{
    const int t = blockIdx.x * 256 + threadIdx.x;   // 4096
    float v = scal_[9] * scal_[9];
    for (int ck = 0; ck < NTK_BLOCKS; ++ck) v += part[(size_t)ck * 4096 + t];
    out[t] = v;
}

// ---------------- host launch ----------------
extern "C" void kernel_launch(void* const* d_in, const int* in_sizes, int n_in,
                              void* d_out, int out_size, void* d_ws, size_t ws_size,
                              hipStream_t stream)
{
    const void* IN[14];
    if (n_in >= 14 && in_sizes[2] == 10 && in_sizes[3] == 1) {
        for (int k = 0; k < 14; ++k) IN[k] = d_in[k];
    } else {
        IN[0] = d_in[0]; IN[1] = d_in[1];
        IN[2] = d_in[12]; IN[3] = d_in[13];
        for (int k = 0; k < 8; ++k) IN[4 + k] = d_in[2 + k];
        IN[12] = d_in[10]; IN[13] = d_in[11];
    }
    const float* x1   = (const float*)IN[0];
    const float* x2   = (const float*)IN[1];
    const float* scal = (const float*)IN[2];
    const int*   cp   = (const int*)IN[3];
    const float* w1 = (const float*)IN[4];  const float* b1 = (const float*)IN[5];
    const float* w2 = (const float*)IN[6];  const float* b2 = (const float*)IN[7];
    const float* w3 = (const float*)IN[8];  const float* b3 = (const float*)IN[9];
    const float* w4 = (const float*)IN[10]; const float* b4 = (const float*)IN[11];
    const float* fcw = (const float*)IN[12];
    float* out = (float*)d_out;

    char* base = (char*)d_ws;
    size_t off = 0;
    auto alloc = [&](size_t bytes) -> char* {
        char* p = base + off;
        off = (off + bytes + 255) & ~(size_t)255;
        return p;
    };
    // JT first. xT (10.84 MB) aliases JT's W3 segment (features 38720..59888,
    // inside W3 [38720,75584)): xT consumers are k_fwd<3,84> and k_wgrad1; after
    // k_wgrad1, W3 is memset to 0 and k_wgrad<10,21> atomically accumulates it.
    // W1/B1/W2 (head memset) and W4 (second head memset) do not overlap xT.
    float* JT = (float*)alloc((size_t)PJ * 128 * 4);      // 58.5 MB
    float* xT = JT + (size_t)OFF_W3 * 128;
    float* p1 = (float*)alloc((size_t)1764 * 64 * 128 * 4);
    float* p2 = (float*)alloc((size_t)441  * 64 * 128 * 4);
    float* p3 = (float*)alloc((size_t)100  * 64 * 128 * 4);
    float* p4 = (float*)alloc((size_t)25   * 64 * 128 * 4);
    unsigned char* m1 = (unsigned char*)alloc((size_t)1764 * 64 * 128);
    unsigned char* m2 = (unsigned char*)alloc((size_t)441  * 64 * 128);
    unsigned char* m3 = (unsigned char*)alloc((size_t)100  * 64 * 128);
    unsigned char* m4 = (unsigned char*)alloc((size_t)25   * 64 * 128);
    float* g1 = (float*)alloc((size_t)1764 * 64 * 128 * 4);
    float* g2 = (float*)alloc((size_t)441  * 64 * 128 * 4);
    float* g3 = (float*)alloc((size_t)100  * 64 * 128 * 4);
    float* g4 = (float*)alloc((size_t)25   * 64 * 128 * 4);
    float* wS1 = (float*)alloc(1728 * 4);
    float* wS2 = (float*)alloc(36864 * 4);
    float* wS3 = (float*)alloc(36864 * 4);
    float* wS4 = (float*)alloc(36864 * 4);
    float* wB2 = (float*)alloc(36864 * 4);
    float* wB3 = (float*)alloc(36864 * 4);
    float* wB4 = (float*)alloc(36864 * 4);
    float* dbp = (float*)alloc((size_t)16 * 64 * 128 * 4);
    // NTK partials (446*16KB = 7.3 MB) alias g1 (57.8 MB): g1 dead after k_dbpart.
    float* ntkp = g1;
    (void)ws_size;

    // ---- zero atomic-accumulated segments: W1+B1+W2 and W4 ----
    hipMemsetAsync(JT, 0, (size_t)OFF_B2 * 128 * 4, stream);
    hipMemsetAsync(JT + (size_t)OFF_W4 * 128, 0, (size_t)36864 * 128 * 4, stream);

    // ---- prep ----
    k_transpose<<<dim3(662, 4), dim3(32, 8), 0, stream>>>(x1, x2, xT);
    k_wprep<<<144, 256, 0, stream>>>(w1, w2, w3, w4, wS1, wS2, wS3, wS4, wB2, wB3, wB4);

    // ---- forward (xT: [3][84][84][128]; p_l: [y][x][64][128]) ----
    // OB=4 for layers 1-2: doubles wave count (latency hiding) vs round-8 OB=8.
    k_fwd<3, 84, 4, 84 * 84 * 128, 84 * 128, 128>
        <<<dim3(21, 16, 21), dim3(128, 2), 0, stream>>>(xT, wS1, b1, p1, m1);
    k_fwd<64, 42, 4, 128, 42 * 64 * 128, 64 * 128>
        <<<dim3(11, 16, 11), dim3(128, 2), 0, stream>>>(p1, wS2, b2, p2, m2);
    k_fwd<64, 21, 4, 128, 21 * 64 * 128, 64 * 128>
        <<<dim3(5, 16, 5), dim3(128, 2), 0, stream>>>(p2, wS3, b3, p3, m3);
    k_fwd<64, 10, 4, 128, 10 * 64 * 128, 64 * 128>
        <<<dim3(3, 16, 3), dim3(128, 2), 0, stream>>>(p3, wS4, b4, p4, m4);

    // ---- seed gamma4 + h segment ----
    k_seed<<<1600, 128, 0, stream>>>(fcw, cp, p4, scal, g4, JT);

    // ---- backward cotangents (dense, pooled-window dedup) ----
    k_bwd<5, 10, 8><<<dim3(3, 8, 5),  dim3(128, 2), 0, stream>>>(g4, m4, wB4, g3);
    k_bwd<10, 21, 8><<<dim3(6, 8, 11), dim3(128, 2), 0, stream>>>(g3, m3, wB3, g2);
    k_bwd<21, 42, 8><<<dim3(11, 8, 21), dim3(128, 2), 0, stream>>>(g2, m2, wB2, g1);

    // ---- weight grads (round-6 form; deeper z-split for occupancy) ----
    k_wgrad<5, 10><<<dim3(32, 32, 2), 128, 0, stream>>>(g4, m4, p3, scal, 6, OFF_W4, JT, 5);
    k_wgrad1<<<dim3(32, 42), 128, 0, stream>>>(g1, m1, xT, scal, JT);
    // xT retired; zero W3 then accumulate it
    hipMemsetAsync(JT + (size_t)OFF_W3 * 128, 0, (size_t)36864 * 128 * 4, stream);
    k_wgrad<10, 21><<<dim3(32, 32, 3), 128, 0, stream>>>(g3, m3, p2, scal, 4, OFF_W3, JT, 7);
    k_wgrad<21, 42><<<dim3(32, 32, 6), 128, 0, stream>>>(g2, m2, p1, scal, 2, OFF_W2, JT, 7);

    // ---- bias grads ----
    k_dbpart<<<dim3(64, 4, 4), 128, 0, stream>>>(g1, g2, g3, g4, m1, m2, m3, m4, dbp);
    k_dbred<<<128, 256, 0, stream>>>(dbp, scal, JT);

    // ---- K = JT1^T . JT2 + s_fcb^2 (ntkp aliases g1; g1 dead after dbpart) ----
    k_ntk<<<NTK_BLOCKS, dim3(16, 16), 0, stream>>>(JT, ntkp);
    k_ntkred<<<16, 256, 0, stream>>>(ntkp, scal, out);
}

// Round 11
// 2214.040 us; speedup vs baseline: 1.3208x; 1.0220x over previous
//
#include <hip/hip_runtime.h>
#include <cstdint>

// ---------------- problem constants ----------------
// S=128 samples (64 x1 + 64 x2) live in the lane dimension of every tensor:
// activations/cotangents/masks are [y][x][ch][s=128] ("CHWN"-style, s innermost).
constexpr int OFF_W1 = 0;        // 64*3*9
constexpr int OFF_B1 = 1728;
constexpr int OFF_W2 = 1792;     // 64*64*9
constexpr int OFF_B2 = 38656;
constexpr int OFF_W3 = 38720;
constexpr int OFF_B3 = 75584;
constexpr int OFF_W4 = 75648;
constexpr int OFF_B4 = 112512;
constexpr int OFF_H  = 112576;   // 1600
constexpr int PJ     = 114176;   // = 223*512

// ---------------- input transpose: [128][3*84*84] -> [3*84*84][128] ----------------
__global__ __launch_bounds__(256) void k_transpose(
    const float* __restrict__ x1, const float* __restrict__ x2, float* __restrict__ xT)
{
    __shared__ float tile[32][33];
    const int c0 = blockIdx.x * 32, s0 = blockIdx.y * 32;
    const int tx = threadIdx.x, ty = threadIdx.y;
#pragma unroll
    for (int k = 0; k < 4; ++k) {
        const int row = s0 + ty + k * 8;          // sample
        const int col = c0 + tx;                  // flat (i,y,x)
        const float* src = (row < 64) ? (x1 + (size_t)row * 21168)
                                      : (x2 + (size_t)(row - 64) * 21168);
        tile[ty + k * 8][tx] = (col < 21168) ? src[col] : 0.f;
    }
    __syncthreads();
#pragma unroll
    for (int k = 0; k < 4; ++k) {
        const int c = c0 + ty + k * 8;
        if (c < 21168) xT[(size_t)c * 128 + (s0 + tx)] = tile[tx][ty + k * 8];
    }
}

// ---------------- weight prep ----------------
// wS_l[i][t][o] = w_l[o][i][t]      (forward, scalar-load friendly)
// wB_l[o][t][i] = w_l[o][i][8-t]    (backward conv-transpose)
__global__ __launch_bounds__(256) void k_wprep(
    const float* __restrict__ w1, const float* __restrict__ w2,
    const float* __restrict__ w3, const float* __restrict__ w4,
    float* __restrict__ wS1, float* __restrict__ wS2, float* __restrict__ wS3,
    float* __restrict__ wS4, float* __restrict__ wB2, float* __restrict__ wB3,
    float* __restrict__ wB4)
{
    const int idx = blockIdx.x * 256 + threadIdx.x;
    if (idx >= 36864) return;
    const int o = idx / 576, rem = idx % 576, i = rem / 9, t = rem % 9;
    wS2[(i * 9 + t) * 64 + o] = w2[idx];
    wS3[(i * 9 + t) * 64 + o] = w3[idx];
    wS4[(i * 9 + t) * 64 + o] = w4[idx];
    wB2[(o * 9 + (8 - t)) * 64 + i] = w2[idx];
    wB3[(o * 9 + (8 - t)) * 64 + i] = w3[idx];
    wB4[(o * 9 + (8 - t)) * 64 + i] = w4[idx];
    if (idx < 1728) {
        const int o1 = idx / 27, r1 = idx % 27, i1 = r1 / 9, t1 = r1 % 9;
        wS1[(i1 * 9 + t1) * 64 + o1] = w1[idx];
    }
}

// ---------------- forward conv3x3(SAME)+bias+relu+maxpool2x2, fused ----------------
// block (128 s-lanes, 2): ty = pooled row within pair. Each thread: OB o's x 2 conv rows x 4 conv cols.
// in strides (floats): i*SI + y*SY + x*SX + lane
template<int CIN, int TIN, int OB, int SI, int SY, int SX>
__global__ __launch_bounds__(256) void k_fwd(
    const float* __restrict__ in, const float* __restrict__ wS,
    const float* __restrict__ bias, float* __restrict__ pout,
    unsigned char* __restrict__ mout)
{
    constexpr int PW = TIN / 2;
    const int lane = threadIdx.x;
    const int x0 = blockIdx.x * 4;
    const int o0 = blockIdx.y * OB;
    const int pr = blockIdx.z * 2 + threadIdx.y;
    if (pr >= PW) return;
    const int cr0 = 2 * pr;

    float acc[OB][2][4];
#pragma unroll
    for (int j = 0; j < OB; ++j)
#pragma unroll
        for (int r = 0; r < 2; ++r)
#pragma unroll
            for (int p = 0; p < 4; ++p) acc[j][r][p] = 0.f;

#pragma unroll 1
    for (int i = 0; i < CIN; ++i) {
        float a[4][6];
#pragma unroll
        for (int rr = 0; rr < 4; ++rr) {
            const int y = cr0 - 1 + rr;
            const bool rok = (unsigned)y < (unsigned)TIN;
#pragma unroll
            for (int cc = 0; cc < 6; ++cc) {
                const int x = x0 - 1 + cc;
                a[rr][cc] = (rok && (unsigned)x < (unsigned)TIN)
                    ? in[(size_t)i * SI + (size_t)y * SY + (size_t)x * SX + lane] : 0.f;
            }
        }
        const float* wrow = wS + (i * 9) * 64 + o0;   // uniform -> s_load
#pragma unroll
        for (int t = 0; t < 9; ++t) {
            const int dy = t / 3, dx = t % 3;
#pragma unroll
            for (int j = 0; j < OB; ++j) {
                const float wv = wrow[t * 64 + j];
#pragma unroll
                for (int r = 0; r < 2; ++r)
#pragma unroll
                    for (int p = 0; p < 4; ++p)
                        acc[j][r][p] = fmaf(wv, a[r + dy][p + dx], acc[j][r][p]);
            }
        }
    }
#pragma unroll
    for (int j = 0; j < OB; ++j) {
        const float b = bias[o0 + j];
#pragma unroll
        for (int q = 0; q < 2; ++q) {
            const int wx = x0 / 2 + q;
            if (wx >= PW) continue;
            const float c00 = fmaxf(acc[j][0][2 * q]     + b, 0.f);
            const float c01 = fmaxf(acc[j][0][2 * q + 1] + b, 0.f);
            const float c10 = fmaxf(acc[j][1][2 * q]     + b, 0.f);
            const float c11 = fmaxf(acc[j][1][2 * q + 1] + b, 0.f);
            float best = c00; int idx = 0;                     // first-strict-max (matches XLA)
            if (c01 > best) { best = c01; idx = 1; }
            if (c10 > best) { best = c10; idx = 2; }
            if (c11 > best) { best = c11; idx = 3; }
            const size_t oi = ((size_t)(pr * PW + wx) * 64 + (o0 + j)) * 128 + lane;
            pout[oi] = best;
            mout[oi] = (unsigned char)(idx | (best > 0.f ? 4 : 0));
        }
    }
}

// ---------------- seed: gamma4 = fc_w[c] reshaped [64][5][5]; J h-segment ----------------
__global__ __launch_bounds__(128) void k_seed(
    const float* __restrict__ fcw, const int* __restrict__ cptr,
    const float* __restrict__ p4, const float* __restrict__ scal_,
    float* __restrict__ g4, float* __restrict__ JT)
{
    const int s = threadIdx.x;
    const int cell = blockIdx.x / 64, o = blockIdx.x % 64;
    const int c = *cptr;
    const int j = o * 25 + cell;                   // CHW flatten of [64][5][5]
    const size_t base = ((size_t)cell * 64 + o) * 128 + s;
    g4[base] = fcw[(size_t)c * 1600 + j];
    JT[(size_t)(OFF_H + j) * 128 + s] = scal_[8] * p4[base];
}

// ---------------- backward: gamma_{l-1} = convT(w_l, u_l), u routed inline ----------------
// gl/ml on TL^2 pooled grid; output dense on TP^2 grid. u_l[y][x][o] = (m==code)?g:0.
// Dedup: the 3x6 dense window touches only 2x4 pooled cells; load those once per o
// (wave-uniform scalar addressing) and route in registers via static selectors.
template<int TL, int TP, int OB>
__global__ __launch_bounds__(256) void k_bwd(
    const float* __restrict__ gl, const unsigned char* __restrict__ ml,
    const float* __restrict__ wB, float* __restrict__ gout)
{
    const int lane = threadIdx.x;
    const int x0 = blockIdx.x * 4;
    const int i0 = blockIdx.y * OB;
    const int row = blockIdx.z * 2 + threadIdx.y;
    if (row >= TP) return;

    // pooled window: rows prA=(row-1)>>1, prB=(row+1)>>1; cols pc0..pc0+3
    const int prA = (row - 1) >> 1;
    const int prB = (row + 1) >> 1;
    const int pc0 = (x0 - 1) >> 1;
    const int rpar = row & 1;
    // rr -> pooled-row slot: rr=0 -> A, rr=1 -> (rpar? A : B), rr=2 -> B
    const int ridx1 = rpar ? 0 : 1;

    float acc[OB][4];
#pragma unroll
    for (int j = 0; j < OB; ++j)
#pragma unroll
        for (int p = 0; p < 4; ++p) acc[j][p] = 0.f;

#pragma unroll 1
    for (int o = 0; o < 64; ++o) {
        // load the 2x4 pooled (mask, gamma) window; invalid cells never match
        int   mv[2][4];
        float gv[2][4];
#pragma unroll
        for (int r2 = 0; r2 < 2; ++r2) {
            const int prr = r2 ? prB : prA;
            const bool rok = (unsigned)prr < (unsigned)TL;
#pragma unroll
            for (int c2 = 0; c2 < 4; ++c2) {
                const int pcc = pc0 + c2;
                const bool ok = rok && (unsigned)pcc < (unsigned)TL;
                if (ok) {
                    const size_t base = ((size_t)(prr * TL + pcc) * 64 + o) * 128 + lane;
                    mv[r2][c2] = ml[base];
                    gv[r2][c2] = gl[base];
                } else {
                    mv[r2][c2] = 255;
                    gv[r2][c2] = 0.f;
                }
            }
        }
        // route into the 3x6 dense window
        float a[3][6];
#pragma unroll
        for (int rr = 0; rr < 3; ++rr) {
            const int ridx = (rr == 0) ? 0 : ((rr == 2) ? 1 : ridx1);
            const int ycode = 4 | (((row - 1 + rr) & 1) << 1);
#pragma unroll
            for (int cc = 0; cc < 6; ++cc) {
                const int cidx = (cc + 1) >> 1;          // {0,1,1,2,2,3}
                const int code = ycode | ((cc + 1) & 1); // x0 even -> x parity = (cc+1)&1
                a[rr][cc] = (mv[ridx][cidx] == code) ? gv[ridx][cidx] : 0.f;
            }
        }
        const float* wrow = wB + (o * 9) * 64 + i0;   // uniform -> s_load
#pragma unroll
        for (int t = 0; t < 9; ++t) {
            const int dy = t / 3, dx = t % 3;
#pragma unroll
            for (int j = 0; j < OB; ++j) {
                const float wv = wrow[t * 64 + j];
#pragma unroll
                for (int p = 0; p < 4; ++p)
                    acc[j][p] = fmaf(wv, a[dy][p + dx], acc[j][p]);
            }
        }
    }
#pragma unroll
    for (int j = 0; j < OB; ++j)
#pragma unroll
        for (int p = 0; p < 4; ++p) {
            const int x = x0 + p;
            if (x < TP)
                gout[((size_t)(row * TP + x) * 64 + (i0 + j)) * 128 + lane] = acc[j][p];
        }
}

// ---------------- weight grads (layers 2..4), pooled-cell 2x2 form ----------------
// dW[o,i,dy,dx] = sum over pooled cells of u*h; ONE (m,g) load pair per pooled cell
// per o serves its 2x2 dense block (u-vmem /4), 4-row x 4-col rotating window
// (h-loads 24->16 per cell). Tile kept at 2o x 2i for VGPR (~96) — round 7's 4-i
// variant hit 152 VGPR / 12% occupancy and regressed. Atomic z-split over wy.
template<int TL, int TIN>
__global__ __launch_bounds__(128) void k_wgrad(
    const float* __restrict__ gl, const unsigned char* __restrict__ ml,
    const float* __restrict__ h, const float* __restrict__ scal_,
    const int scalIdx, const int joff, float* __restrict__ JT, const int wychunk)
{
    const int s = threadIdx.x;
    const int o0 = blockIdx.x * 2, i0 = blockIdx.y * 2;
    const int wy0 = blockIdx.z * wychunk;
    const int wy1 = (wy0 + wychunk < TL) ? wy0 + wychunk : TL;

    float acc[2][2][9];
#pragma unroll
    for (int a = 0; a < 2; ++a)
#pragma unroll
        for (int b = 0; b < 2; ++b)
#pragma unroll
            for (int t = 0; t < 9; ++t) acc[a][b][t] = 0.f;

#pragma unroll 1
    for (int wy = wy0; wy < wy1; ++wy) {
        // window rows ry = 2wy-1 .. 2wy+2 ; slot c holds dense col 2wx-1+c
        float hw[2][4][4];
#pragma unroll
        for (int ji = 0; ji < 2; ++ji)
#pragma unroll
            for (int r = 0; r < 4; ++r) {
                const int ry = 2 * wy - 1 + r;
                const bool rok = (unsigned)ry < (unsigned)TIN;
                hw[ji][r][0] = 0.f;   // col -1
#pragma unroll
                for (int c = 1; c < 4; ++c) {
                    const int col = c - 1;           // cols 0,1,2 (< TIN always)
                    hw[ji][r][c] = rok
                        ? h[((size_t)(ry * TIN + col) * 64 + i0 + ji) * 128 + s] : 0.f;
                }
            }
#pragma unroll 1
        for (int wx = 0; wx < TL; ++wx) {
            // one (m,g) pair per pooled cell per jo -> 4 routed dense values
            float uu[2][2][2];
#pragma unroll
            for (int jo = 0; jo < 2; ++jo) {
                const size_t base = ((size_t)(wy * TL + wx) * 64 + o0 + jo) * 128 + s;
                const int mv = ml[base];
                const float gv = gl[base];
#pragma unroll
                for (int yy = 0; yy < 2; ++yy)
#pragma unroll
                    for (int xx = 0; xx < 2; ++xx)
                        uu[jo][yy][xx] = (mv == (4 | (yy << 1) | xx)) ? gv : 0.f;
            }
            // dense (y,x)=(2wy+yy, 2wx+xx); h[y+dy-1][x+dx-1] = hw[r=yy+dy][slot=xx+dx]
#pragma unroll
            for (int jo = 0; jo < 2; ++jo)
#pragma unroll
                for (int yy = 0; yy < 2; ++yy)
#pragma unroll
                    for (int xx = 0; xx < 2; ++xx) {
                        const float uv = uu[jo][yy][xx];
#pragma unroll
                        for (int ji = 0; ji < 2; ++ji)
#pragma unroll
                            for (int dy = 0; dy < 3; ++dy)
#pragma unroll
                                for (int dx = 0; dx < 3; ++dx)
                                    acc[jo][ji][dy * 3 + dx] =
                                        fmaf(uv, hw[ji][yy + dy][xx + dx],
                                             acc[jo][ji][dy * 3 + dx]);
                    }
            // shift window 2 cols; load dense cols 2wx+3, 2wx+4 into slots 2,3
            if (wx + 1 < TL) {
#pragma unroll
                for (int ji = 0; ji < 2; ++ji)
#pragma unroll
                    for (int r = 0; r < 4; ++r) {
                        hw[ji][r][0] = hw[ji][r][2];
                        hw[ji][r][1] = hw[ji][r][3];
                    }
#pragma unroll
                for (int c = 2; c < 4; ++c) {
                    const int col = 2 * wx + 1 + c;   // 2(wx+1)-1+c
                    const bool cok = col < TIN;
#pragma unroll
                    for (int ji = 0; ji < 2; ++ji)
#pragma unroll
                        for (int r = 0; r < 4; ++r) {
                            const int ry = 2 * wy - 1 + r;
                            hw[ji][r][c] = (cok && (unsigned)ry < (unsigned)TIN)
                                ? h[((size_t)(ry * TIN + col) * 64 + i0 + ji) * 128 + s]
                                : 0.f;
                        }
                }
            }
        }
    }
    const float sc = scal_[scalIdx];
#pragma unroll
    for (int jo = 0; jo < 2; ++jo)
#pragma unroll
        for (int ji = 0; ji < 2; ++ji)
#pragma unroll
            for (int t = 0; t < 9; ++t) {
                const int feat = joff + ((o0 + jo) * 64 + (i0 + ji)) * 9 + t;
                atomicAdd(&JT[(size_t)feat * 128 + s], sc * acc[jo][ji][t]);
            }
}

// ---------------- weight grad layer 1: dense-routed u, lane=s, coalesced ----------------
// grid: (32 o-pairs, 42 pooled rows wy), block 128. Covers dense rows y=2wy, 2wy+1.
// Atomic split over wy into pre-zeroed W1 segment of JT. xT: [3][84][84][128].
__global__ __launch_bounds__(128) void k_wgrad1(
    const float* __restrict__ g1, const unsigned char* __restrict__ m1,
    const float* __restrict__ xT, const float* __restrict__ scal_,
    float* __restrict__ JT)
{
    const int s = threadIdx.x;
    const int o0 = blockIdx.x * 2;
    const int wy = blockIdx.y;

    float acc[2][3][9];
#pragma unroll
    for (int oo = 0; oo < 2; ++oo)
#pragma unroll
        for (int i = 0; i < 3; ++i)
#pragma unroll
            for (int t = 0; t < 9; ++t) acc[oo][i][t] = 0.f;

    // window rows ry = 2wy-1 .. 2wy+2 ; rotating col window idx (k+dx+2)%3
    float hw[3][4][3];
#pragma unroll
    for (int i = 0; i < 3; ++i)
#pragma unroll
        for (int r = 0; r < 4; ++r) {
            const int ry = 2 * wy - 1 + r;
            hw[i][r][2] = 0.f;   // col -1
            hw[i][r][1] = 0.f;
            hw[i][r][0] = ((unsigned)ry < 84u)
                ? xT[((size_t)i * 7056 + ry * 84) * 128 + s] : 0.f;  // col 0
        }
    const int cellrow = wy * 42;

#pragma unroll 1
    for (int xb = 0; xb < 84; xb += 3) {
#pragma unroll
        for (int k = 0; k < 3; ++k) {
            const int x = xb + k;
            const int xn = x + 1;
            const bool cok = xn < 84;
#pragma unroll
            for (int i = 0; i < 3; ++i)
#pragma unroll
                for (int r = 0; r < 4; ++r) {
                    const int ry = 2 * wy - 1 + r;
                    hw[i][r][(k + 1) % 3] = (cok && (unsigned)ry < 84u)
                        ? xT[((size_t)i * 7056 + ry * 84 + xn) * 128 + s] : 0.f;
                }
            const int wx = x >> 1;
            const int xbit = x & 1;
            float u[2][2];
#pragma unroll
            for (int oo = 0; oo < 2; ++oo) {
                const size_t base = ((size_t)(cellrow + wx) * 64 + o0 + oo) * 128 + s;
                const int mv = m1[base];
                const float gv = g1[base];
                u[oo][0] = (mv == (4 | 0 | xbit)) ? gv : 0.f;   // dense row even
                u[oo][1] = (mv == (4 | 2 | xbit)) ? gv : 0.f;   // dense row odd
            }
#pragma unroll
            for (int oo = 0; oo < 2; ++oo)
#pragma unroll
                for (int yy = 0; yy < 2; ++yy)
#pragma unroll
                    for (int i = 0; i < 3; ++i)
#pragma unroll
                        for (int dy = 0; dy < 3; ++dy)
#pragma unroll
                            for (int dx = 0; dx < 3; ++dx)
                                acc[oo][i][dy * 3 + dx] =
                                    fmaf(u[oo][yy], hw[i][yy + dy][(k + dx + 2) % 3],
                                         acc[oo][i][dy * 3 + dx]);
        }
    }
    const float sc = scal_[0];
#pragma unroll
    for (int oo = 0; oo < 2; ++oo)
#pragma unroll
        for (int i = 0; i < 3; ++i)
#pragma unroll
            for (int t = 0; t < 9; ++t)
                atomicAdd(&JT[(size_t)(OFF_W1 + (o0 + oo) * 27 + i * 9 + t) * 128 + s],
                          sc * acc[oo][i][t]);
}

// ---------------- bias grads: partials then reduce ----------------
__global__ __launch_bounds__(128) void k_dbpart(
    const float* __restrict__ g1, const float* __restrict__ g2,
    const float* __restrict__ g3, const float* __restrict__ g4,
    const unsigned char* __restrict__ m1, const unsigned char* __restrict__ m2,
    const unsigned char* __restrict__ m3, const unsigned char* __restrict__ m4,
    float* __restrict__ part)
{
    const int s = threadIdx.x;
    const int o = blockIdx.x, chunk = blockIdx.y, layer = blockIdx.z;
    const float* g; const unsigned char* m; int nc;
    if (layer == 0)      { g = g1; m = m1; nc = 1764; }
    else if (layer == 1) { g = g2; m = m2; nc = 441; }
    else if (layer == 2) { g = g3; m = m3; nc = 100; }
    else                 { g = g4; m = m4; nc = 25; }
    const int c0 = chunk * nc / 4, c1 = (chunk + 1) * nc / 4;
    float acc = 0.f;
    for (int cell = c0; cell < c1; ++cell) {
        const size_t base = ((size_t)cell * 64 + o) * 128 + s;
        acc += (m[base] & 4) ? g[base] : 0.f;
    }
    part[((size_t)(layer * 4 + chunk) * 64 + o) * 128 + s] = acc;
}

__global__ __launch_bounds__(256) void k_dbred(
    const float* __restrict__ part, const float* __restrict__ scal_,
    float* __restrict__ JT)
{
    const int idx = blockIdx.x * 256 + threadIdx.x;   // 4*64*128
    const int layer = idx >> 13, o = (idx >> 7) & 63, s = idx & 127;
    float v = 0.f;
#pragma unroll
    for (int ch = 0; ch < 4; ++ch)
        v += part[((size_t)(layer * 4 + ch) * 64 + o) * 128 + s];
    const int offb[4] = {OFF_B1, OFF_B2, OFF_B3, OFF_B4};
    JT[(size_t)(offb[layer] + o) * 128 + s] = scal_[2 * layer + 1] * v;
}

// ---------------- NTK GEMM: per-block partials, then reduce (+fc_b const) ----------------
constexpr int NTK_BLOCKS = 446;   // 446 * 8 * 32 = 114176 = PJ
__global__ __launch_bounds__(256) void k_ntk(const float* __restrict__ JT,
                                             float* __restrict__ part)
{
    __shared__ float As[32][64], Bs[32][64];
    const int tx = threadIdx.x, ty = threadIdx.y;
    const int t = ty * 16 + tx;
    float acc[4][4];
#pragma unroll
    for (int a = 0; a < 4; ++a)
#pragma unroll
        for (int b = 0; b < 4; ++b) acc[a][b] = 0.f;

    for (int ch = 0; ch < 8; ++ch) {
        const int k0 = (blockIdx.x * 8 + ch) * 32;
        __syncthreads();
#pragma unroll
        for (int q = 0; q < 4; ++q) {
            const int fidx = q * 256 + t;          // float4 index within [32][128]
            const int row = fidx >> 5;
            const int c4 = (fidx & 31) * 4;
            const float4 v = *(const float4*)&JT[(size_t)(k0 + row) * 128 + c4];
            if (c4 < 64) *(float4*)&As[row][c4] = v;
            else         *(float4*)&Bs[row][c4 - 64] = v;
        }
        __syncthreads();
#pragma unroll
        for (int k = 0; k < 32; ++k) {
            const float4 av = *(const float4*)&As[k][ty * 4];
            const float4 bv = *(const float4*)&Bs[k][tx * 4];
            acc[0][0] = fmaf(av.x, bv.x, acc[0][0]);
            acc[0][1] = fmaf(av.x, bv.y, acc[0][1]);
            acc[0][2] = fmaf(av.x, bv.z, acc[0][2]);
            acc[0][3] = fmaf(av.x, bv.w, acc[0][3]);
            acc[1][0] = fmaf(av.y, bv.x, acc[1][0]);
            acc[1][1] = fmaf(av.y, bv.y, acc[1][1]);
            acc[1][2] = fmaf(av.y, bv.z, acc[1][2]);
            acc[1][3] = fmaf(av.y, bv.w, acc[1][3]);
            acc[2][0] = fmaf(av.z, bv.x, acc[2][0]);
            acc[2][1] = fmaf(av.z, bv.y, acc[2][1]);
            acc[2][2] = fmaf(av.z, bv.z, acc[2][2]);
            acc[2][3] = fmaf(av.z, bv.w, acc[2][3]);
            acc[3][0] = fmaf(av.w, bv.x, acc[3][0]);
            acc[3][1] = fmaf(av.w, bv.y, acc[3][1]);
            acc[3][2] = fmaf(av.w, bv.z, acc[3][2]);
            acc[3][3] = fmaf(av.w, bv.w, acc[3][3]);
        }
    }
#pragma unroll
    for (int a = 0; a < 4; ++a)
#pragma unroll
        for (int b = 0; b < 4; ++b)
            part[(size_t)blockIdx.x * 4096 + (ty * 4 + a) * 64 + (tx * 4 + b)] = acc[a][b];
}

__global__ __launch_bounds__(256) void k_ntkred(
    const float* __restrict__ part, const float* __restrict__ scal_,
    float* __restrict__ out)
{
    const int t = blockIdx.x * 256 + threadIdx.x;   // 4096
    float v = scal_[9] * scal_[9];
    for (int ck = 0; ck < NTK_BLOCKS; ++ck) v += part[(size_t)ck * 4096 + t];
    out[t] = v;
}

// ---------------- host launch ----------------
extern "C" void kernel_launch(void* const* d_in, const int* in_sizes, int n_in,
                              void* d_out, int out_size, void* d_ws, size_t ws_size,
                              hipStream_t stream)
{
    const void* IN[14];
    if (n_in >= 14 && in_sizes[2] == 10 && in_sizes[3] == 1) {
        for (int k = 0; k < 14; ++k) IN[k] = d_in[k];
    } else {
        IN[0] = d_in[0]; IN[1] = d_in[1];
        IN[2] = d_in[12]; IN[3] = d_in[13];
        for (int k = 0; k < 8; ++k) IN[4 + k] = d_in[2 + k];
        IN[12] = d_in[10]; IN[13] = d_in[11];
    }
    const float* x1   = (const float*)IN[0];
    const float* x2   = (const float*)IN[1];
    const float* scal = (const float*)IN[2];
    const int*   cp   = (const int*)IN[3];
    const float* w1 = (const float*)IN[4];  const float* b1 = (const float*)IN[5];
    const float* w2 = (const float*)IN[6];  const float* b2 = (const float*)IN[7];
    const float* w3 = (const float*)IN[8];  const float* b3 = (const float*)IN[9];
    const float* w4 = (const float*)IN[10]; const float* b4 = (const float*)IN[11];
    const float* fcw = (const float*)IN[12];
    float* out = (float*)d_out;

    char* base = (char*)d_ws;
    size_t off = 0;
    auto alloc = [&](size_t bytes) -> char* {
        char* p = base + off;
        off = (off + bytes + 255) & ~(size_t)255;
        return p;
    };
    // JT first. xT (10.84 MB) aliases JT's W3 segment (features 38720..59888,
    // inside W3 [38720,75584)): xT consumers are k_fwd<3,84> and k_wgrad1; after
    // k_wgrad1, W3 is memset to 0 and k_wgrad<10,21> atomically accumulates it.
    // W1/B1/W2 (head memset) and W4 (second head memset) do not overlap xT.
    float* JT = (float*)alloc((size_t)PJ * 128 * 4);      // 58.5 MB
    float* xT = JT + (size_t)OFF_W3 * 128;
    float* p1 = (float*)alloc((size_t)1764 * 64 * 128 * 4);
    float* p2 = (float*)alloc((size_t)441  * 64 * 128 * 4);
    float* p3 = (float*)alloc((size_t)100  * 64 * 128 * 4);
    float* p4 = (float*)alloc((size_t)25   * 64 * 128 * 4);
    unsigned char* m1 = (unsigned char*)alloc((size_t)1764 * 64 * 128);
    unsigned char* m2 = (unsigned char*)alloc((size_t)441  * 64 * 128);
    unsigned char* m3 = (unsigned char*)alloc((size_t)100  * 64 * 128);
    unsigned char* m4 = (unsigned char*)alloc((size_t)25   * 64 * 128);
    float* g1 = (float*)alloc((size_t)1764 * 64 * 128 * 4);
    float* g2 = (float*)alloc((size_t)441  * 64 * 128 * 4);
    float* g3 = (float*)alloc((size_t)100  * 64 * 128 * 4);
    float* g4 = (float*)alloc((size_t)25   * 64 * 128 * 4);
    float* wS1 = (float*)alloc(1728 * 4);
    float* wS2 = (float*)alloc(36864 * 4);
    float* wS3 = (float*)alloc(36864 * 4);
    float* wS4 = (float*)alloc(36864 * 4);
    float* wB2 = (float*)alloc(36864 * 4);
    float* wB3 = (float*)alloc(36864 * 4);
    float* wB4 = (float*)alloc(36864 * 4);
    float* dbp = (float*)alloc((size_t)16 * 64 * 128 * 4);
    // NTK partials (446*16KB = 7.3 MB) alias g1 (57.8 MB): g1 dead after k_dbpart.
    float* ntkp = g1;
    (void)ws_size;

    // ---- zero atomic-accumulated segments: W1+B1+W2 and W4 ----
    hipMemsetAsync(JT, 0, (size_t)OFF_B2 * 128 * 4, stream);
    hipMemsetAsync(JT + (size_t)OFF_W4 * 128, 0, (size_t)36864 * 128 * 4, stream);

    // ---- prep ----
    k_transpose<<<dim3(662, 4), dim3(32, 8), 0, stream>>>(x1, x2, xT);
    k_wprep<<<144, 256, 0, stream>>>(w1, w2, w3, w4, wS1, wS2, wS3, wS4, wB2, wB3, wB4);

    // ---- forward (xT: [3][84][84][128]; p_l: [y][x][64][128]) ----
    k_fwd<3, 84, 4, 84 * 84 * 128, 84 * 128, 128>
        <<<dim3(21, 16, 21), dim3(128, 2), 0, stream>>>(xT, wS1, b1, p1, m1);
    k_fwd<64, 42, 4, 128, 42 * 64 * 128, 64 * 128>
        <<<dim3(11, 16, 11), dim3(128, 2), 0, stream>>>(p1, wS2, b2, p2, m2);
    k_fwd<64, 21, 4, 128, 21 * 64 * 128, 64 * 128>
        <<<dim3(5, 16, 5), dim3(128, 2), 0, stream>>>(p2, wS3, b3, p3, m3);
    k_fwd<64, 10, 4, 128, 10 * 64 * 128, 64 * 128>
        <<<dim3(3, 16, 3), dim3(128, 2), 0, stream>>>(p3, wS4, b4, p4, m4);

    // ---- seed gamma4 + h segment ----
    k_seed<<<1600, 128, 0, stream>>>(fcw, cp, p4, scal, g4, JT);

    // ---- backward cotangents (dense, pooled-window dedup) ----
    k_bwd<5, 10, 8><<<dim3(3, 8, 5),  dim3(128, 2), 0, stream>>>(g4, m4, wB4, g3);
    k_bwd<10, 21, 8><<<dim3(6, 8, 11), dim3(128, 2), 0, stream>>>(g3, m3, wB3, g2);
    k_bwd<21, 42, 8><<<dim3(11, 8, 21), dim3(128, 2), 0, stream>>>(g2, m2, wB2, g1);

    // ---- weight grads (pooled-cell 2x2 form; z-split over wy) ----
    k_wgrad<5, 10><<<dim3(32, 32, 2), 128, 0, stream>>>(g4, m4, p3, scal, 6, OFF_W4, JT, 3);
    k_wgrad1<<<dim3(32, 42), 128, 0, stream>>>(g1, m1, xT, scal, JT);
    // xT retired; zero W3 then accumulate it
    hipMemsetAsync(JT + (size_t)OFF_W3 * 128, 0, (size_t)36864 * 128 * 4, stream);
    k_wgrad<10, 21><<<dim3(32, 32, 3), 128, 0, stream>>>(g3, m3, p2, scal, 4, OFF_W3, JT, 4);
    k_wgrad<21, 42><<<dim3(32, 32, 6), 128, 0, stream>>>(g2, m2, p1, scal, 2, OFF_W2, JT, 4);

    // ---- bias grads ----
    k_dbpart<<<dim3(64, 4, 4), 128, 0, stream>>>(g1, g2, g3, g4, m1, m2, m3, m4, dbp);
    k_dbred<<<128, 256, 0, stream>>>(dbp, scal, JT);

    // ---- K = JT1^T . JT2 + s_fcb^2 (ntkp aliases g1; g1 dead after dbpart) ----
    k_ntk<<<NTK_BLOCKS, dim3(16, 16), 0, stream>>>(JT, ntkp);
    k_ntkred<<<16, 256, 0, stream>>>(ntkp, scal, out);
}